// Round 3
// baseline (2735.260 us; speedup 1.0000x reference)
//
#include <hip/hip_runtime.h>
#include <hip/hip_bf16.h>
#include <cstddef>

using bf16 = __hip_bfloat16;
typedef short s8v __attribute__((ext_vector_type(8)));
typedef __bf16 b8v __attribute__((ext_vector_type(8)));
typedef float f4v __attribute__((ext_vector_type(4)));

// ---------------- problem constants ----------------
constexpr int cB = 8, cL = 12, cN = 207, cD = 512, cH = 8, cF = 2048;
constexpr int cO = 12, cNG = 3;
constexpr int cT  = cL * cN;          // 2484
constexpr int cBT = cB * cT;          // 19872
constexpr int cE  = cD / cH;          // 64
constexpr size_t SZ = (size_t)cBT * cD;   // 10,174,464
constexpr long DD = (long)cD * cD;    // 262144
constexpr int KVCH = 12;              // kv_part chunks (2484 = 12*207)
constexpr int CHLEN = 207;

// ---------------- helpers ----------------
__device__ __forceinline__ float tofl(bf16 v) { return __bfloat162float(v); }
__device__ __forceinline__ bf16 f2b(float v) { return __float2bfloat16(v); }
__device__ __forceinline__ float b2f_raw(short s) {
    unsigned u = ((unsigned)(unsigned short)s) << 16;
    float f; __builtin_memcpy(&f, &u, 4); return f;
}
__device__ __forceinline__ short f2b_raw(float v) {
    bf16 t = __float2bfloat16(v);
    short s; __builtin_memcpy(&s, &t, 2); return s;
}
__device__ __forceinline__ float ldin(const void* p, size_t i, int bf) {
    return bf ? __bfloat162float(((const bf16*)p)[i]) : ((const float*)p)[i];
}
__device__ __forceinline__ void stout(void* p, size_t i, float v, int bf) {
    if (bf) ((bf16*)p)[i] = f2b(v);
    else    ((float*)p)[i] = v;
}
__device__ __forceinline__ float gelu_f(float x) {
    float x3 = x * x * x;
    return 0.5f * x * (1.f + tanhf(0.7978845608028654f * (x + 0.044715f * x3)));
}
// async global->LDS, 16B per lane; lds must be wave-uniform base (HW adds lane*16)
__device__ __forceinline__ void gload16(void* lds, const void* g) {
    __builtin_amdgcn_global_load_lds(
        (const __attribute__((address_space(1))) unsigned int*)g,
        (__attribute__((address_space(3))) unsigned int*)lds,
        16, 0, 0);
}

// ---------------- dtype detection ----------------
__global__ void detect_kernel(const void* __restrict__ x, int* __restrict__ flag) {
    __shared__ float red[4];
    int t = threadIdx.x;
    float m = 0.f;
    for (int i = t; i < 1024; i += 256) {
        float v = __bfloat162float(((const bf16*)x)[i]);
        if (v != v) v = 1e30f;
        m = fmaxf(m, fabsf(v));
    }
#pragma unroll
    for (int off = 32; off; off >>= 1) m = fmaxf(m, __shfl_down(m, off));
    if ((t & 63) == 0) red[t >> 6] = m;
    __syncthreads();
    if (t == 0) {
        float mm = fmaxf(fmaxf(red[0], red[1]), fmaxf(red[2], red[3]));
        flag[0] = (mm < 1e3f) ? 1 : 0;
    }
}

// ---------------- convert kernels ----------------
__global__ void cvt_copy(bf16* __restrict__ dst, const void* __restrict__ src,
                         const int* __restrict__ fl, size_t n, size_t soff) {
    int bf = *fl;
#pragma unroll
    for (int j = 0; j < 4; ++j) {
        size_t i = (size_t)blockIdx.x * 1024 + (size_t)j * 256 + threadIdx.x;
        if (i < n) dst[i] = f2b(ldin(src, soff + i, bf));
    }
}
// dst[n*K + k] = src[soff + k*N + n]
__global__ void cvt_tr(bf16* __restrict__ dst, const void* __restrict__ src,
                       const int* __restrict__ fl, int K, int N, size_t soff) {
    int bf = *fl;
    size_t idx = (size_t)blockIdx.x * 256 + threadIdx.x;
    if (idx >= (size_t)K * N) return;
    int n = (int)(idx / K), k = (int)(idx % K);
    dst[idx] = f2b(ldin(src, soff + (size_t)k * N + n, bf));
}

// ---------------- bijective XCD swizzle (m204) ----------------
__device__ __forceinline__ void xcd_swz(unsigned& bx, unsigned& by, unsigned& bz) {
    unsigned gx = gridDim.x, gy = gridDim.y;
    unsigned nwg = gx * gy * gridDim.z;
    unsigned orig = (blockIdx.z * gy + blockIdx.y) * gx + blockIdx.x;
    unsigned q = nwg >> 3, r = nwg & 7;
    unsigned xcd = orig & 7, sub = orig >> 3;
    unsigned wg = (xcd < r ? xcd * (q + 1) : r * (q + 1) + (xcd - r) * q) + sub;
    bx = wg % gx;
    unsigned t1 = wg / gx;
    by = t1 % gy;
    bz = t1 / gy;
}

// ---------------- fast MFMA GEMM (TRB=true only, K%32==0) ----------------
// C[bz](MxN) = A[bz](MxK,row-major) @ B^T ; B row-major NxK
// m97 structure: 128x128 tile, BK=32, linear LDS, global_load_lds width=16
// OUT: 0=bf16 store, 1=f32 store, 2=f32 +=
template <int BIAS, int ACT, int OUT>
__global__ __launch_bounds__(256) void mgemm_f(
    const bf16* __restrict__ Ab, const bf16* __restrict__ Bb, void* __restrict__ Cb,
    const bf16* __restrict__ bias,
    int M, int N, int K, int lda, int ldb, int ldc,
    long sA, long sB, long sC, int modA, int modB, long aoff0, long boff0)
{
    unsigned bxu, byu, bzu;
    xcd_swz(bxu, byu, bzu);
    int bz = (int)bzu;
    const bf16* A = Ab + aoff0 + (size_t)(modA ? (bz % modA) : bz) * sA;
    const bf16* B = Bb + boff0 + (size_t)(modB ? (bz % modB) : bz) * sB;
    size_t coff = (size_t)bz * sC;

    int m0 = (int)byu * 128, n0 = (int)bxu * 128;
    int tid = threadIdx.x;
    int lane = tid & 63, w = tid >> 6;
    int wm = (w & 1) * 64, wn = (w >> 1) * 64;
    int l16 = lane & 15, quad = lane >> 4;

    __shared__ short As[128 * 32];   // linear [row][k], 64B rows
    __shared__ short Bs[128 * 32];

    // staging geometry: thread t covers row t/4 (+64 for pass 1), k-col (t%4)*8
    int srow = tid >> 2, scol = (tid & 3) << 3;
    int ar0 = m0 + srow;      if (ar0 >= M) ar0 = M - 1;   // clamp: garbage rows never stored
    int ar1 = m0 + srow + 64; if (ar1 >= M) ar1 = M - 1;
    int br0 = n0 + srow;      if (br0 >= N) br0 = N - 1;
    int br1 = n0 + srow + 64; if (br1 >= N) br1 = N - 1;
    const bf16* ap0 = A + (size_t)ar0 * lda + scol;
    const bf16* ap1 = A + (size_t)ar1 * lda + scol;
    const bf16* bp0 = B + (size_t)br0 * ldb + scol;
    const bf16* bp1 = B + (size_t)br1 * ldb + scol;
    short* al0 = &As[w * 512];          // wave-uniform bases
    short* al1 = &As[2048 + w * 512];
    short* bl0 = &Bs[w * 512];
    short* bl1 = &Bs[2048 + w * 512];

    f4v acc[4][4] = {};

    int nk = K >> 5;
    for (int kk = 0; kk < nk; ++kk) {
        gload16(al0, ap0);
        gload16(al1, ap1);
        gload16(bl0, bp0);
        gload16(bl1, bp1);
        ap0 += 32; ap1 += 32; bp0 += 32; bp1 += 32;
        __syncthreads();   // compiler drains vmcnt before s_barrier
        b8v af[4], bfr[4];
#pragma unroll
        for (int mi = 0; mi < 4; ++mi)
            af[mi] = *(const b8v*)&As[(wm + mi * 16 + l16) * 32 + quad * 8];
#pragma unroll
        for (int ni = 0; ni < 4; ++ni)
            bfr[ni] = *(const b8v*)&Bs[(wn + ni * 16 + l16) * 32 + quad * 8];
#pragma unroll
        for (int mi = 0; mi < 4; ++mi)
#pragma unroll
            for (int ni = 0; ni < 4; ++ni)
                acc[mi][ni] = __builtin_amdgcn_mfma_f32_16x16x32_bf16(af[mi], bfr[ni], acc[mi][ni], 0, 0, 0);
        __syncthreads();
    }

    // ---- epilogue ----
    bf16* Co = (bf16*)Cb;
    float* Cf = (float*)Cb;
#pragma unroll
    for (int mi = 0; mi < 4; ++mi) {
#pragma unroll
        for (int ni = 0; ni < 4; ++ni) {
            int gn = n0 + wn + ni * 16 + l16;
            float bv = 0.f;
            if (BIAS == 1 && gn < N) bv = tofl(bias[gn]);
#pragma unroll
            for (int r = 0; r < 4; ++r) {
                int gm = m0 + wm + mi * 16 + quad * 4 + r;
                if (gm < M && gn < N) {
                    float v = acc[mi][ni][r] + bv;
                    if (BIAS == 2) v += tofl(bias[gm]);
                    if (ACT == 1) v = gelu_f(v);
                    if (ACT == 2) v = v > 0.f ? v + 1.f : expf(v);
                    size_t ci = coff + (size_t)gm * ldc + gn;
                    if (OUT == 0) Co[ci] = f2b(v);
                    else if (OUT == 1) Cf[ci] = v;
                    else Cf[ci] += v;
                }
            }
        }
    }
}

// ---------------- generic MFMA GEMM (kept for TRB=false / K%32!=0) ----------------
template <bool TRB, int BIAS, int ACT, int OUT>
__global__ __launch_bounds__(256) void mgemm(
    const bf16* __restrict__ Ab, const bf16* __restrict__ Bb, void* __restrict__ Cb,
    const bf16* __restrict__ bias,
    int M, int N, int K, int lda, int ldb, int ldc,
    long sA, long sB, long sC, int modA, int modB, long aoff0, long boff0)
{
    unsigned bxu, byu, bzu;
    xcd_swz(bxu, byu, bzu);
    int bz = (int)bzu;
    const bf16* A = Ab + aoff0 + (size_t)(modA ? (bz % modA) : bz) * sA;
    const bf16* B = Bb + boff0 + (size_t)(modB ? (bz % modB) : bz) * sB;
    size_t coff = (size_t)bz * sC;

    int m0 = (int)byu * 128, n0 = (int)bxu * 128;
    int tid = threadIdx.x;
    int lane = tid & 63, w = tid >> 6;
    int wm = (w & 1) * 64, wn = (w >> 1) * 64;
    int l16 = lane & 15, quad = lane >> 4;

    __shared__ short Asl[128 * 40];
    __shared__ short Bsl[128 * 40];

    f4v acc[4][4] = {};

    for (int k0 = 0; k0 < K; k0 += 32) {
        // ---- stage A: rows m, K-contiguous ----
        for (int g = tid; g < 512; g += 256) {
            int r = g >> 2, kg = (g & 3) << 3;
            int gr = m0 + r, gk = k0 + kg;
            s8v val = {0, 0, 0, 0, 0, 0, 0, 0};
            if (gr < M) {
                const short* src = (const short*)A + (size_t)gr * lda + gk;
                if (gk + 8 <= K) val = *(const s8v*)src;
                else {
#pragma unroll
                    for (int j = 0; j < 8; ++j) if (gk + j < K) val[j] = src[j];
                }
            }
            *(s8v*)&Asl[r * 40 + kg] = val;
        }
        // ---- stage B ----
        if (TRB) {
            for (int g = tid; g < 512; g += 256) {
                int r = g >> 2, kg = (g & 3) << 3;
                int gr = n0 + r, gk = k0 + kg;
                s8v val = {0, 0, 0, 0, 0, 0, 0, 0};
                if (gr < N) {
                    const short* src = (const short*)B + (size_t)gr * ldb + gk;
                    if (gk + 8 <= K) val = *(const s8v*)src;
                    else {
#pragma unroll
                        for (int j = 0; j < 8; ++j) if (gk + j < K) val[j] = src[j];
                    }
                }
                *(s8v*)&Bsl[r * 40 + kg] = val;
            }
        } else {
            for (int g = tid; g < 512; g += 256) {
                int kr = g >> 4, ng = (g & 15) << 3;
                int gk = k0 + kr, gn = n0 + ng;
                s8v val = {0, 0, 0, 0, 0, 0, 0, 0};
                if (gk < K) {
                    const short* src = (const short*)B + (size_t)gk * ldb + gn;
                    if (gn + 8 <= N) val = *(const s8v*)src;
                    else {
#pragma unroll
                        for (int j = 0; j < 8; ++j) if (gn + j < N) val[j] = src[j];
                    }
                }
#pragma unroll
                for (int j = 0; j < 8; ++j) Bsl[(ng + j) * 40 + kr] = val[j];
            }
        }
        __syncthreads();
        // ---- compute ----
        b8v af[4], bfr[4];
#pragma unroll
        for (int mi = 0; mi < 4; ++mi)
            af[mi] = *(const b8v*)&Asl[(wm + mi * 16 + l16) * 40 + quad * 8];
#pragma unroll
        for (int ni = 0; ni < 4; ++ni)
            bfr[ni] = *(const b8v*)&Bsl[(wn + ni * 16 + l16) * 40 + quad * 8];
#pragma unroll
        for (int mi = 0; mi < 4; ++mi)
#pragma unroll
            for (int ni = 0; ni < 4; ++ni)
                acc[mi][ni] = __builtin_amdgcn_mfma_f32_16x16x32_bf16(af[mi], bfr[ni], acc[mi][ni], 0, 0, 0);
        __syncthreads();
    }

    // ---- epilogue ----
    bf16* Co = (bf16*)Cb;
    float* Cf = (float*)Cb;
#pragma unroll
    for (int mi = 0; mi < 4; ++mi) {
#pragma unroll
        for (int ni = 0; ni < 4; ++ni) {
            int gn = n0 + wn + ni * 16 + l16;
            float bv = 0.f;
            if (BIAS == 1 && gn < N) bv = tofl(bias[gn]);
#pragma unroll
            for (int r = 0; r < 4; ++r) {
                int gm = m0 + wm + mi * 16 + quad * 4 + r;
                if (gm < M && gn < N) {
                    float v = acc[mi][ni][r] + bv;
                    if (BIAS == 2) v += tofl(bias[gm]);
                    if (ACT == 1) v = gelu_f(v);
                    if (ACT == 2) v = v > 0.f ? v + 1.f : expf(v);
                    size_t ci = coff + (size_t)gm * ldc + gn;
                    if (OUT == 0) Co[ci] = f2b(v);
                    else if (OUT == 1) Cf[ci] = v;
                    else Cf[ci] += v;
                }
            }
        }
    }
}

// ---------------- attention micro-kernels ----------------
// per-chunk partial kv/ksum: chunk c covers t in [c*207, (c+1)*207)
__global__ __launch_bounds__(256) void kv_part(
    const bf16* __restrict__ Kf, const bf16* __restrict__ V,
    float* __restrict__ kvp, float* __restrict__ ksp)
{
    int bh = blockIdx.x, c = blockIdx.y;
    int b = bh >> 3, h = bh & 7;
    int tbase = c * CHLEN, tend = tbase + CHLEN;
    __shared__ float ks[32][64];
    __shared__ float vs[32][64];
    int tid = threadIdx.x;
    int e = tid >> 2, dg = tid & 3;
    f4v a0 = {}, a1 = {}, a2 = {}, a3 = {};
    float ksacc = 0.f;
    int srow = tid >> 3, sc = (tid & 7) << 3;
    for (int t0 = tbase; t0 < tend; t0 += 32) {
        int t = t0 + srow;
        s8v kk8 = {0, 0, 0, 0, 0, 0, 0, 0};
        s8v vv8 = {0, 0, 0, 0, 0, 0, 0, 0};
        if (t < tend) {
            size_t off2 = ((size_t)(b * cT + t)) * cD + h * cE + sc;
            kk8 = *(const s8v*)((const short*)Kf + off2);
            vv8 = *(const s8v*)((const short*)V + off2);
        }
        __syncthreads();   // previous compute done before overwrite
        f4v kf0, kf1, vf0, vf1;
#pragma unroll
        for (int j = 0; j < 4; ++j) {
            kf0[j] = b2f_raw(kk8[j]);     kf1[j] = b2f_raw(kk8[4 + j]);
            vf0[j] = b2f_raw(vv8[j]);     vf1[j] = b2f_raw(vv8[4 + j]);
        }
        *(f4v*)&ks[srow][sc] = kf0;  *(f4v*)&ks[srow][sc + 4] = kf1;
        *(f4v*)&vs[srow][sc] = vf0;  *(f4v*)&vs[srow][sc + 4] = vf1;
        __syncthreads();
#pragma unroll 8
        for (int tt = 0; tt < 32; ++tt) {
            float kf = ks[tt][e];
            ksacc += kf;
            const float* vp2 = &vs[tt][dg * 16];
            f4v v0 = *(const f4v*)(vp2);
            f4v v1 = *(const f4v*)(vp2 + 4);
            f4v v2 = *(const f4v*)(vp2 + 8);
            f4v v3 = *(const f4v*)(vp2 + 12);
            a0 += kf * v0;  a1 += kf * v1;  a2 += kf * v2;  a3 += kf * v3;
        }
    }
    size_t base = (((size_t)c * 64 + bh) * cE + e) * cE + dg * 16;
    *(f4v*)&kvp[base]      = a0;
    *(f4v*)&kvp[base + 4]  = a1;
    *(f4v*)&kvp[base + 8]  = a2;
    *(f4v*)&kvp[base + 12] = a3;
    if (dg == 0) ksp[(size_t)c * 4096 + bh * cE + e] = ksacc;
}

__global__ void kv_reduce(const float* __restrict__ kvp, const float* __restrict__ ksp,
                          float* __restrict__ kvf, float* __restrict__ ksf)
{
    size_t idx = (size_t)blockIdx.x * 256 + threadIdx.x;
    if (idx < 262144) {
        float s = 0.f;
#pragma unroll
        for (int c2 = 0; c2 < KVCH; ++c2) s += kvp[(size_t)c2 * 262144 + idx];
        kvf[idx] = s;
    } else if (idx < 262144 + 4096) {
        size_t i = idx - 262144;
        float s = 0.f;
#pragma unroll
        for (int c2 = 0; c2 < KVCH; ++c2) s += ksp[(size_t)c2 * 4096 + i];
        ksf[i] = s;
    }
}

// O = (q . kv) / (q . ksum + eps), kv tile staged in LDS once per block.
// grid (KVCH, 64); block 256 = 4 waves; wave w handles rows [w*52, ...) of the chunk.
__global__ __launch_bounds__(256) void attn_o2(
    const bf16* __restrict__ Qf, const float* __restrict__ kv,
    const float* __restrict__ ksum, bf16* __restrict__ O)
{
    int c = blockIdx.x, bh = blockIdx.y;
    int b = bh >> 3, h = bh & 7;
    __shared__ float kvs[64][64];     // kvs[d][swz(e)] = kv[e][d], XOR-swizzled e-groups
    int tid = threadIdx.x;
    const float* kvsrc = kv + (size_t)bh * 4096;
    for (int i = tid; i < 4096; i += 256) {
        int e2 = i >> 6, d2 = i & 63;
        int g = e2 >> 2;
        kvs[d2][(((g ^ (d2 & 15)) & 15) << 2) | (e2 & 3)] = kvsrc[i];
    }
    int l = tid & 63, w = tid >> 6;
    float kse = ksum[bh * 64 + l];
    __syncthreads();

    int rbeg = w * 52;
    int rend = (w == 3) ? CHLEN : rbeg + 52;
    const short* Qs = (const short*)Qf;
    for (int r0 = rbeg; r0 < rend; r0 += 4) {
        float qv[4];
#pragma unroll
        for (int j = 0; j < 4; ++j) {
            int rr = r0 + j;
            qv[j] = (rr < rend)
                ? b2f_raw(Qs[((size_t)(b * cT + c * CHLEN + rr)) * cD + h * cE + l])
                : 0.f;
        }
        float den[4];
#pragma unroll
        for (int j = 0; j < 4; ++j) {
            float p = qv[j] * kse;
#pragma unroll
            for (int s = 32; s; s >>= 1) p += __shfl_xor(p, s);
            den[j] = 1.f / (p + 1e-6f);
        }
        float oa[4] = {0.f, 0.f, 0.f, 0.f};
#pragma unroll
        for (int g = 0; g < 16; ++g) {
            f4v kvv = *(const f4v*)&kvs[l][((g ^ (l & 15)) & 15) << 2];
#pragma unroll
            for (int j = 0; j < 4; ++j) {
                float q0 = __shfl(qv[j], 4 * g + 0);
                float q1 = __shfl(qv[j], 4 * g + 1);
                float q2 = __shfl(qv[j], 4 * g + 2);
                float q3 = __shfl(qv[j], 4 * g + 3);
                oa[j] += q0 * kvv[0] + q1 * kvv[1] + q2 * kvv[2] + q3 * kvv[3];
            }
        }
#pragma unroll
        for (int j = 0; j < 4; ++j) {
            int rr = r0 + j;
            if (rr < rend) {
                size_t ooff = ((size_t)(b * cT + c * CHLEN + rr)) * cD + h * cE + l;
                O[ooff] = f2b(oa[j] * den[j]);
            }
        }
    }
}

// out = LN(a + b) * g + be   (bf16 in/out; optional dynamic second write)
template <int DUAL>
__global__ __launch_bounds__(256) void add_ln(
    const bf16* __restrict__ a, const bf16* __restrict__ b,
    const bf16* __restrict__ g, const bf16* __restrict__ be,
    bf16* __restrict__ out, void* __restrict__ dyn_out,
    const int* __restrict__ fl, size_t dyn_off)
{
    int row = blockIdx.x;
    size_t base = (size_t)row * cD;
    int t = threadIdx.x;
    float x0 = tofl(a[base + t]) + tofl(b[base + t]);
    float x1 = tofl(a[base + t + 256]) + tofl(b[base + t + 256]);
    float s1 = x0 + x1, s2 = x0 * x0 + x1 * x1;
#pragma unroll
    for (int off = 32; off; off >>= 1) { s1 += __shfl_down(s1, off); s2 += __shfl_down(s2, off); }
    __shared__ float r1[4], r2[4];
    int w = t >> 6;
    if ((t & 63) == 0) { r1[w] = s1; r2[w] = s2; }
    __syncthreads();
    float S1 = r1[0] + r1[1] + r1[2] + r1[3];
    float S2 = r2[0] + r2[1] + r2[2] + r2[3];
    float mean = S1 * (1.f / cD);
    float var = S2 * (1.f / cD) - mean * mean;
    float inv = rsqrtf(var + 1e-5f);
    float y0 = (x0 - mean) * inv * tofl(g[t]) + tofl(be[t]);
    float y1 = (x1 - mean) * inv * tofl(g[t + 256]) + tofl(be[t + 256]);
    out[base + t] = f2b(y0);
    out[base + t + 256] = f2b(y1);
    if (DUAL) {
        int bf = *fl;
        stout(dyn_out, dyn_off + base + t, y0, bf);
        stout(dyn_out, dyn_off + base + t + 256, y1, bf);
    }
}

// XT[b,o,n,d] = sum_l ttw[o,l]*t_out[b,l,n,d] + ttb[o]   (8 d-elems per thread)
__global__ void tout2_kernel(const bf16* __restrict__ tout, const bf16* __restrict__ ttw,
                             const bf16* __restrict__ ttb, bf16* __restrict__ XT)
{
    size_t idx8 = ((size_t)blockIdx.x * 256 + threadIdx.x) * 8;
    if (idx8 >= SZ) return;
    int d = (int)(idx8 & (cD - 1));
    size_t r = idx8 >> 9;
    int n = (int)(r % cN);
    size_t r2 = r / cN;
    int o = (int)(r2 % cO);
    int b = (int)(r2 / cO);
    float tb = tofl(ttb[o]);
    float acc[8];
#pragma unroll
    for (int j = 0; j < 8; ++j) acc[j] = tb;
    size_t base = ((size_t)b * cT + n) * cD + d;
    const short* ts = (const short*)tout;
#pragma unroll
    for (int l = 0; l < cL; ++l) {
        float wv = tofl(ttw[o * cL + l]);
        s8v v = *(const s8v*)(ts + base + (size_t)l * cN * cD);
#pragma unroll
        for (int j = 0; j < 8; ++j) acc[j] += wv * b2f_raw(v[j]);
    }
    s8v ov;
#pragma unroll
    for (int j = 0; j < 8; ++j) ov[j] = f2b_raw(acc[j]);
    *(s8v*)((short*)XT + idx8) = ov;
}

// At3[s][m][n] = adj[n,m,s]  (row stride 208, bf16)
__global__ void extract_adjT(const void* __restrict__ adj, bf16* __restrict__ At3,
                             const int* __restrict__ fl)
{
    int bf = *fl;
    int idx = blockIdx.x * 256 + threadIdx.x;
    if (idx >= cNG * cN * cN) return;
    int s = idx / (cN * cN);
    int rem = idx - s * cN * cN;
    int m = rem / cN;
    int n = rem - m * cN;
    At3[((size_t)s * cN + m) * 208 + n] = f2b(ldin(adj, (size_t)(n * cN + m) * cNG + s, bf));
}

// dts[b,o,n,d] = (G + gb[o,d]) * bng[o,d] + bnb[o,d]
__global__ void dts_kernel(const float* __restrict__ g, const bf16* __restrict__ gb,
                           const bf16* __restrict__ bng, const bf16* __restrict__ bnb,
                           void* __restrict__ out, const int* __restrict__ fl)
{
    int bf = *fl;
    size_t idx = (size_t)blockIdx.x * 256 + threadIdx.x;
    if (idx >= SZ) return;
    int d = idx & (cD - 1);
    size_t r = idx >> 9;
    int o = (int)((r / cN) % cO);
    int od = o * cD + d;
    float v = (g[idx] + tofl(gb[od])) * tofl(bng[od]) + tofl(bnb[od]);
    stout(out, idx, v, bf);
}

// ---------------- host helpers ----------------
static inline dim3 g2(int M, int N, int bz) { return dim3((N + 127) / 128, (M + 127) / 128, bz); }

static void run_attn(const bf16* Aq, const bf16* Akv, const bf16* wT, const bf16* bias,
                     bf16* Q, bf16* K, bf16* V, bf16* outp,
                     float* kvp, float* ksp, float* kvf, float* ksf, hipStream_t s)
{
    mgemm_f<1, 2, 0><<<g2(cBT, cD, 1), 256, 0, s>>>(Aq,  wT,          Q, bias,          cBT, cD, cD, cD, cD, cD, 0, 0, 0, 1, 1, 0, 0);
    mgemm_f<1, 2, 0><<<g2(cBT, cD, 1), 256, 0, s>>>(Akv, wT + DD,     K, bias + cD,     cBT, cD, cD, cD, cD, cD, 0, 0, 0, 1, 1, 0, 0);
    mgemm_f<1, 0, 0><<<g2(cBT, cD, 1), 256, 0, s>>>(Akv, wT + 2 * DD, V, bias + 2 * cD, cBT, cD, cD, cD, cD, cD, 0, 0, 0, 1, 1, 0, 0);
    kv_part<<<dim3(64, KVCH), 256, 0, s>>>(K, V, kvp, ksp);
    kv_reduce<<<1040, 256, 0, s>>>(kvp, ksp, kvf, ksf);
    attn_o2<<<dim3(KVCH, 64), 256, 0, s>>>(Q, kvf, ksf, Q);
    mgemm_f<1, 0, 0><<<g2(cBT, cD, 1), 256, 0, s>>>(Q, wT + 3 * DD, outp, bias + 3 * cD, cBT, cD, cD, cD, cD, cD, 0, 0, 0, 1, 1, 0, 0);
}

static void run_ffn(const bf16* inp, const bf16* w1T, const bf16* b1,
                    const bf16* w2T, const bf16* b2, bf16* mid, bf16* outp, hipStream_t s)
{
    const int MH = cBT / 2;
    for (int h = 0; h < 2; ++h) {
        const bf16* ip = inp + (size_t)h * MH * cD;
        bf16* op = outp + (size_t)h * MH * cD;
        mgemm_f<1, 1, 0><<<g2(MH, cF, 1), 256, 0, s>>>(ip, w1T, mid, b1, MH, cF, cD, cD, cD, cF, 0, 0, 0, 1, 1, 0, 0);
        mgemm_f<1, 0, 0><<<g2(MH, cD, 1), 256, 0, s>>>(mid, w2T, op, b2, MH, cD, cF, cF, cF, cD, 0, 0, 0, 1, 1, 0, 0);
    }
}

// ---------------- entry point ----------------
extern "C" void kernel_launch(void* const* d_in, const int* in_sizes, int n_in,
                              void* d_out, int out_size, void* d_ws, size_t ws_size,
                              hipStream_t stream)
{
    const void* x    = d_in[0];
    const void* st   = d_in[1];
    const void* adj  = d_in[3];
    const void* eqw  = d_in[4];
    const void* eqb  = d_in[5];
    const void* ew1  = d_in[6];
    const void* eb1  = d_in[7];
    const void* ew2  = d_in[8];
    const void* eb2  = d_in[9];
    const void* elng = d_in[10];
    const void* elnb = d_in[11];
    const void* dsw  = d_in[12];
    const void* dsb  = d_in[13];
    const void* dcw  = d_in[14];
    const void* dcb  = d_in[15];
    const void* dw1  = d_in[16];
    const void* db1  = d_in[17];
    const void* dw2  = d_in[18];
    const void* db2  = d_in[19];
    const void* dlng = d_in[20];
    const void* dlnb = d_in[21];
    const void* ttw  = d_in[22];
    const void* ttb  = d_in[23];
    const void* tsw  = d_in[24];
    const void* tsb  = d_in[25];
    const void* gw   = d_in[26];
    const void* gb   = d_in[27];
    const void* bng  = d_in[28];
    const void* bnb  = d_in[29];

    bf16* P = (bf16*)d_ws;
    size_t off = 0;
    auto alloc = [&](size_t n) { size_t o = off; off += (n + 127) & ~(size_t)127; return o; };

    size_t eqwT = alloc(4 * DD);
    size_t dswT = alloc(4 * DD);
    size_t dcwT = alloc(4 * DD);
    size_t ew1T = alloc((size_t)cD * cF);
    size_t ew2T = alloc((size_t)cD * cF);
    size_t dw1T = alloc((size_t)cD * cF);
    size_t dw2T = alloc((size_t)cD * cF);
    size_t gwB  = alloc((size_t)cO * cD * 4608);
    size_t tswB = alloc((size_t)cN * cD);
    size_t xb   = alloc(SZ);
    size_t stb  = alloc(SZ);
    size_t eqbB = alloc(4 * cD), eb1B = alloc(cF), eb2B = alloc(cD);
    size_t elngB = alloc(2 * cD), elnbB = alloc(2 * cD);
    size_t dsbB = alloc(4 * cD), dcbB = alloc(4 * cD);
    size_t db1B = alloc(cF), db2B = alloc(cD);
    size_t dlngB = alloc(3 * cD), dlnbB = alloc(3 * cD);
    size_t ttwB = alloc(cO * cL), ttbB = alloc(cO), tsbB = alloc(cN);
    size_t gbB = alloc(cO * cD), bngB = alloc(cO * cD), bnbB = alloc(cO * cD);
    size_t at3 = alloc((size_t)cNG * cN * 208);
    size_t slots = alloc(6 * SZ);
    bf16* S[6];
    for (int i = 0; i < 6; ++i) S[i] = P + slots + (size_t)i * SZ;

    float* F0  = (float*)(P + off);
    float* kvp = F0;                              // KVCH*64*64*64
    float* ksp = kvp + (size_t)KVCH * 262144;     // KVCH*4096
    float* kvf = ksp + (size_t)KVCH * 4096;       // 64*64*64
    float* ksf = kvf + 262144;                    // 4096
    int* flag  = (int*)(ksf + 4096);

    detect_kernel<<<1, 256, 0, stream>>>(x, flag);

    // ---- converts ----
    for (int i = 0; i < 4; ++i) {
        cvt_tr<<<1024, 256, 0, stream>>>(P + eqwT + i * DD, eqw, flag, cD, cD, (size_t)i * DD);
        cvt_tr<<<1024, 256, 0, stream>>>(P + dswT + i * DD, dsw, flag, cD, cD, (size_t)i * DD);
        cvt_tr<<<1024, 256, 0, stream>>>(P + dcwT + i * DD, dcw, flag, cD, cD, (size_t)i * DD);
    }
    cvt_tr<<<4096, 256, 0, stream>>>(P + ew1T, ew1, flag, cD, cF, 0);
    cvt_tr<<<4096, 256, 0, stream>>>(P + ew2T, ew2, flag, cF, cD, 0);
    cvt_tr<<<4096, 256, 0, stream>>>(P + dw1T, dw1, flag, cD, cF, 0);
    cvt_tr<<<4096, 256, 0, stream>>>(P + dw2T, dw2, flag, cF, cD, 0);
    cvt_copy<<<27648, 256, 0, stream>>>(P + gwB, gw, flag, (size_t)cO * cD * 4608, 0);
    cvt_copy<<<104, 256, 0, stream>>>(P + tswB, tsw, flag, (size_t)cN * cD, 0);
    cvt_copy<<<(int)((SZ + 1023) / 1024), 256, 0, stream>>>(P + xb, x, flag, SZ, 0);
    cvt_copy<<<(int)((SZ + 1023) / 1024), 256, 0, stream>>>(P + stb, st, flag, SZ, 0);
    cvt_copy<<<2, 256, 0, stream>>>(P + eqbB, eqb, flag, 4 * cD, 0);
    cvt_copy<<<2, 256, 0, stream>>>(P + eb1B, eb1, flag, cF, 0);
    cvt_copy<<<1, 256, 0, stream>>>(P + eb2B, eb2, flag, cD, 0);
    cvt_copy<<<1, 256, 0, stream>>>(P + elngB, elng, flag, 2 * cD, 0);
    cvt_copy<<<1, 256, 0, stream>>>(P + elnbB, elnb, flag, 2 * cD, 0);
    cvt_copy<<<2, 256, 0, stream>>>(P + dsbB, dsb, flag, 4 * cD, 0);
    cvt_copy<<<2, 256, 0, stream>>>(P + dcbB, dcb, flag, 4 * cD, 0);
    cvt_copy<<<2, 256, 0, stream>>>(P + db1B, db1, flag, cF, 0);
    cvt_copy<<<1, 256, 0, stream>>>(P + db2B, db2, flag, cD, 0);
    cvt_copy<<<2, 256, 0, stream>>>(P + dlngB, dlng, flag, 3 * cD, 0);
    cvt_copy<<<2, 256, 0, stream>>>(P + dlnbB, dlnb, flag, 3 * cD, 0);
    cvt_copy<<<1, 256, 0, stream>>>(P + ttwB, ttw, flag, cO * cL, 0);
    cvt_copy<<<1, 256, 0, stream>>>(P + ttbB, ttb, flag, cO, 0);
    cvt_copy<<<1, 256, 0, stream>>>(P + tsbB, tsb, flag, cN, 0);
    cvt_copy<<<6, 256, 0, stream>>>(P + gbB, gb, flag, cO * cD, 0);
    cvt_copy<<<6, 256, 0, stream>>>(P + bngB, bng, flag, cO * cD, 0);
    cvt_copy<<<6, 256, 0, stream>>>(P + bnbB, bnb, flag, cO * cD, 0);

    // ===== encoder =====
    run_attn(P + xb, P + xb, P + eqwT, P + eqbB, S[0], S[1], S[2], S[3], kvp, ksp, kvf, ksf, stream);
    add_ln<0><<<cBT, 256, 0, stream>>>(P + xb, S[3], P + elngB, P + elnbB, S[4], nullptr, flag, 0);   // y
    run_ffn(S[4], P + ew1T, P + eb1B, P + ew2T, P + eb2B, S[0], S[2], stream);
    add_ln<0><<<cBT, 256, 0, stream>>>(S[4], S[2], P + elngB + cD, P + elnbB + cD, S[5], nullptr, flag, 0);  // t_out

    // ===== decoder self-attn =====
    run_attn(P + stb, P + stb, P + dswT, P + dsbB, S[0], S[1], S[2], S[3], kvp, ksp, kvf, ksf, stream);
    add_ln<0><<<cBT, 256, 0, stream>>>(P + stb, S[3], P + dlngB, P + dlnbB, S[4], nullptr, flag, 0);  // q1

    // ===== decoder cross-attn (Q from q1, KV from t_out) =====
    run_attn(S[4], S[5], P + dcwT, P + dcbB, S[0], S[1], S[2], S[3], kvp, ksp, kvf, ksf, stream);
    add_ln<0><<<cBT, 256, 0, stream>>>(S[4], S[3], P + dlngB + cD, P + dlnbB + cD, S[4], nullptr, flag, 0);  // q2 (in-place)

    // ===== decoder FFN + s_out =====
    run_ffn(S[4], P + dw1T, P + db1B, P + dw2T, P + db2B, S[0], S[2], stream);
    add_ln<1><<<cBT, 256, 0, stream>>>(S[4], S[2], P + dlngB + 2 * cD, P + dlnbB + 2 * cD, S[3], d_out, flag, SZ);

    // ===== temporal projection X_T -> S0 =====
    tout2_kernel<<<(int)(SZ / 2048), 256, 0, stream>>>(S[5], P + ttwB, P + ttbB, S[0]);

    // ===== adaptive adjacency AadT[bz][m][n] (ldc=208) -> S1 =====
    mgemm_f<2, 0, 0><<<g2(cN, cN, cB * cO), 256, 0, stream>>>(
        P + tswB, S[3], S[1], P + tsbB, cN, cN, cD, cD, cD, 208,
        0, (long)cN * cD, (long)cN * 208, 1, 0, 0, 0);

    extract_adjT<<<(cNG * cN * cN + 255) / 256, 256, 0, stream>>>(adj, P + at3, flag);

    // ===== graph diffusion + GCN =====
    float* G = (float*)S[4];           // S4+S5 = SZ floats

    auto accum = [&](const bf16* Feat, int f) {
        mgemm_f<0, 0, 2><<<g2(cN, cD, cB * cO), 256, 0, stream>>>(
            Feat, P + gwB, G, nullptr, cN, cD, cD, cD, 4608, cD,
            (long)cN * cD, (long)cD * 4608, (long)cN * cD, 0, cO, 0, (long)f * cD);
    };
    auto featmul = [&](const bf16* A, long sA, int modA, long aoff0, const bf16* Fin, bf16* Fout) {
        mgemm<false, 0, 0, 0><<<g2(cN, cD, cB * cO), 256, 0, stream>>>(
            A, Fin, Fout, nullptr, cN, cD, cN, 208, cD, cD,
            sA, (long)cN * cD, (long)cN * cD, modA, 0, aoff0, 0);
    };

    // first accumulate WRITES G (OUT=1) -> no zerof pass needed
    mgemm_f<0, 0, 1><<<g2(cN, cD, cB * cO), 256, 0, stream>>>(
        S[0], P + gwB, G, nullptr, cN, cD, cD, cD, 4608, cD,
        (long)cN * cD, (long)cD * 4608, (long)cN * cD, 0, cO, 0, 0);
    for (int s = 0; s < cNG; ++s) {
        featmul(P + at3, 0, 1, (long)s * cN * 208, S[0], S[3]);
        accum(S[3], 2 * s + 1);
        featmul(P + at3, 0, 1, (long)s * cN * 208, S[3], S[2]);
        accum(S[2], 2 * s + 2);
    }
    featmul(S[1], (long)cN * 208, 0, 0, S[0], S[3]);
    accum(S[3], 7);
    featmul(S[1], (long)cN * 208, 0, 0, S[3], S[2]);
    accum(S[2], 8);

    // ===== epilogue =====
    dts_kernel<<<(int)((SZ + 255) / 256), 256, 0, stream>>>(G, P + gbB, P + bngB, P + bnbB, d_out, flag);
}

// Round 4
// 2306.995 us; speedup vs baseline: 1.1856x; 1.1856x over previous
//
#include <hip/hip_runtime.h>
#include <hip/hip_bf16.h>
#include <cstddef>

using bf16 = __hip_bfloat16;
typedef short s8v __attribute__((ext_vector_type(8)));
typedef __bf16 b8v __attribute__((ext_vector_type(8)));
typedef float f4v __attribute__((ext_vector_type(4)));

// ---------------- problem constants ----------------
constexpr int cB = 8, cL = 12, cN = 207, cD = 512, cH = 8, cF = 2048;
constexpr int cO = 12, cNG = 3;
constexpr int cT  = cL * cN;          // 2484
constexpr int cBT = cB * cT;          // 19872
constexpr int cE  = cD / cH;          // 64
constexpr size_t SZ = (size_t)cBT * cD;   // 10,174,464
constexpr long DD = (long)cD * cD;    // 262144
constexpr int KVCH = 12;              // kv_part chunks (2484 = 12*207)
constexpr int CHLEN = 207;

// ---------------- helpers ----------------
__device__ __forceinline__ float tofl(bf16 v) { return __bfloat162float(v); }
__device__ __forceinline__ bf16 f2b(float v) { return __float2bfloat16(v); }
__device__ __forceinline__ float b2f_raw(short s) {
    unsigned u = ((unsigned)(unsigned short)s) << 16;
    float f; __builtin_memcpy(&f, &u, 4); return f;
}
__device__ __forceinline__ short f2b_raw(float v) {
    bf16 t = __float2bfloat16(v);
    short s; __builtin_memcpy(&s, &t, 2); return s;
}
__device__ __forceinline__ float ldin(const void* p, size_t i, int bf) {
    return bf ? __bfloat162float(((const bf16*)p)[i]) : ((const float*)p)[i];
}
__device__ __forceinline__ void stout(void* p, size_t i, float v, int bf) {
    if (bf) ((bf16*)p)[i] = f2b(v);
    else    ((float*)p)[i] = v;
}
__device__ __forceinline__ float gelu_f(float x) {
    float x3 = x * x * x;
    return 0.5f * x * (1.f + tanhf(0.7978845608028654f * (x + 0.044715f * x3)));
}
// async global->LDS, 16B per lane; lds must be wave-uniform base (HW adds lane*16)
__device__ __forceinline__ void gload16(void* lds, const void* g) {
    __builtin_amdgcn_global_load_lds(
        (const __attribute__((address_space(1))) unsigned int*)g,
        (__attribute__((address_space(3))) unsigned int*)lds,
        16, 0, 0);
}

// ---------------- dtype detection ----------------
__global__ void detect_kernel(const void* __restrict__ x, int* __restrict__ flag) {
    __shared__ float red[4];
    int t = threadIdx.x;
    float m = 0.f;
    for (int i = t; i < 1024; i += 256) {
        float v = __bfloat162float(((const bf16*)x)[i]);
        if (v != v) v = 1e30f;
        m = fmaxf(m, fabsf(v));
    }
#pragma unroll
    for (int off = 32; off; off >>= 1) m = fmaxf(m, __shfl_down(m, off));
    if ((t & 63) == 0) red[t >> 6] = m;
    __syncthreads();
    if (t == 0) {
        float mm = fmaxf(fmaxf(red[0], red[1]), fmaxf(red[2], red[3]));
        flag[0] = (mm < 1e3f) ? 1 : 0;
    }
}

// ---------------- convert kernels ----------------
__global__ void cvt_copy(bf16* __restrict__ dst, const void* __restrict__ src,
                         const int* __restrict__ fl, size_t n, size_t soff) {
    int bf = *fl;
#pragma unroll
    for (int j = 0; j < 4; ++j) {
        size_t i = (size_t)blockIdx.x * 1024 + (size_t)j * 256 + threadIdx.x;
        if (i < n) dst[i] = f2b(ldin(src, soff + i, bf));
    }
}
// dst[n*K + k] = src[soff + k*N + n]
__global__ void cvt_tr(bf16* __restrict__ dst, const void* __restrict__ src,
                       const int* __restrict__ fl, int K, int N, size_t soff) {
    int bf = *fl;
    size_t idx = (size_t)blockIdx.x * 256 + threadIdx.x;
    if (idx >= (size_t)K * N) return;
    int n = (int)(idx / K), k = (int)(idx % K);
    dst[idx] = f2b(ldin(src, soff + (size_t)k * N + n, bf));
}

// ---------------- bijective XCD swizzle (m204) ----------------
__device__ __forceinline__ void xcd_swz(unsigned& bx, unsigned& by, unsigned& bz) {
    unsigned gx = gridDim.x, gy = gridDim.y;
    unsigned nwg = gx * gy * gridDim.z;
    unsigned orig = (blockIdx.z * gy + blockIdx.y) * gx + blockIdx.x;
    unsigned q = nwg >> 3, r = nwg & 7;
    unsigned xcd = orig & 7, sub = orig >> 3;
    unsigned wg = (xcd < r ? xcd * (q + 1) : r * (q + 1) + (xcd - r) * q) + sub;
    bx = wg % gx;
    unsigned t1 = wg / gx;
    by = t1 % gy;
    bz = t1 / gy;
}

// ---------------- fast MFMA GEMM (TRB=true only, K%32==0) ----------------
// C[bz](MxN) = A[bz](MxK,row-major) @ B^T ; B row-major NxK
// m97 structure: 128x128 tile, BK=32, linear LDS, global_load_lds width=16
// OUT: 0=bf16 store, 1=f32 store, 2=f32 +=
template <int BIAS, int ACT, int OUT>
__global__ __launch_bounds__(256) void mgemm_f(
    const bf16* __restrict__ Ab, const bf16* __restrict__ Bb, void* __restrict__ Cb,
    const bf16* __restrict__ bias,
    int M, int N, int K, int lda, int ldb, int ldc,
    long sA, long sB, long sC, int modA, int modB, long aoff0, long boff0)
{
    unsigned bxu, byu, bzu;
    xcd_swz(bxu, byu, bzu);
    int bz = (int)bzu;
    const bf16* A = Ab + aoff0 + (size_t)(modA ? (bz % modA) : bz) * sA;
    const bf16* B = Bb + boff0 + (size_t)(modB ? (bz % modB) : bz) * sB;
    size_t coff = (size_t)bz * sC;

    int m0 = (int)byu * 128, n0 = (int)bxu * 128;
    int tid = threadIdx.x;
    int lane = tid & 63, w = tid >> 6;
    int wm = (w & 1) * 64, wn = (w >> 1) * 64;
    int l16 = lane & 15, quad = lane >> 4;

    __shared__ short As[128 * 32];   // linear [row][k], 64B rows
    __shared__ short Bs[128 * 32];

    // staging geometry: thread t covers row t/4 (+64 for pass 1), k-col (t%4)*8
    int srow = tid >> 2, scol = (tid & 3) << 3;
    int ar0 = m0 + srow;      if (ar0 >= M) ar0 = M - 1;   // clamp: garbage rows never stored
    int ar1 = m0 + srow + 64; if (ar1 >= M) ar1 = M - 1;
    int br0 = n0 + srow;      if (br0 >= N) br0 = N - 1;
    int br1 = n0 + srow + 64; if (br1 >= N) br1 = N - 1;
    const bf16* ap0 = A + (size_t)ar0 * lda + scol;
    const bf16* ap1 = A + (size_t)ar1 * lda + scol;
    const bf16* bp0 = B + (size_t)br0 * ldb + scol;
    const bf16* bp1 = B + (size_t)br1 * ldb + scol;
    short* al0 = &As[w * 512];          // wave-uniform bases
    short* al1 = &As[2048 + w * 512];
    short* bl0 = &Bs[w * 512];
    short* bl1 = &Bs[2048 + w * 512];

    f4v acc[4][4] = {};

    int nk = K >> 5;
    for (int kk = 0; kk < nk; ++kk) {
        gload16(al0, ap0);
        gload16(al1, ap1);
        gload16(bl0, bp0);
        gload16(bl1, bp1);
        ap0 += 32; ap1 += 32; bp0 += 32; bp1 += 32;
        __syncthreads();   // compiler drains vmcnt before s_barrier
        b8v af[4], bfr[4];
#pragma unroll
        for (int mi = 0; mi < 4; ++mi)
            af[mi] = *(const b8v*)&As[(wm + mi * 16 + l16) * 32 + quad * 8];
#pragma unroll
        for (int ni = 0; ni < 4; ++ni)
            bfr[ni] = *(const b8v*)&Bs[(wn + ni * 16 + l16) * 32 + quad * 8];
#pragma unroll
        for (int mi = 0; mi < 4; ++mi)
#pragma unroll
            for (int ni = 0; ni < 4; ++ni)
                acc[mi][ni] = __builtin_amdgcn_mfma_f32_16x16x32_bf16(af[mi], bfr[ni], acc[mi][ni], 0, 0, 0);
        __syncthreads();
    }

    // ---- epilogue ----
    bf16* Co = (bf16*)Cb;
    float* Cf = (float*)Cb;
#pragma unroll
    for (int mi = 0; mi < 4; ++mi) {
#pragma unroll
        for (int ni = 0; ni < 4; ++ni) {
            int gn = n0 + wn + ni * 16 + l16;
            float bv = 0.f;
            if (BIAS == 1 && gn < N) bv = tofl(bias[gn]);
#pragma unroll
            for (int r = 0; r < 4; ++r) {
                int gm = m0 + wm + mi * 16 + quad * 4 + r;
                if (gm < M && gn < N) {
                    float v = acc[mi][ni][r] + bv;
                    if (BIAS == 2) v += tofl(bias[gm]);
                    if (ACT == 1) v = gelu_f(v);
                    if (ACT == 2) v = v > 0.f ? v + 1.f : expf(v);
                    size_t ci = coff + (size_t)gm * ldc + gn;
                    if (OUT == 0) Co[ci] = f2b(v);
                    else if (OUT == 1) Cf[ci] = v;
                    else Cf[ci] += v;
                }
            }
        }
    }
}

// ---------------- generic MFMA GEMM (kept for TRB=false / K%32!=0) ----------------
template <bool TRB, int BIAS, int ACT, int OUT>
__global__ __launch_bounds__(256) void mgemm(
    const bf16* __restrict__ Ab, const bf16* __restrict__ Bb, void* __restrict__ Cb,
    const bf16* __restrict__ bias,
    int M, int N, int K, int lda, int ldb, int ldc,
    long sA, long sB, long sC, int modA, int modB, long aoff0, long boff0)
{
    unsigned bxu, byu, bzu;
    xcd_swz(bxu, byu, bzu);
    int bz = (int)bzu;
    const bf16* A = Ab + aoff0 + (size_t)(modA ? (bz % modA) : bz) * sA;
    const bf16* B = Bb + boff0 + (size_t)(modB ? (bz % modB) : bz) * sB;
    size_t coff = (size_t)bz * sC;

    int m0 = (int)byu * 128, n0 = (int)bxu * 128;
    int tid = threadIdx.x;
    int lane = tid & 63, w = tid >> 6;
    int wm = (w & 1) * 64, wn = (w >> 1) * 64;
    int l16 = lane & 15, quad = lane >> 4;

    __shared__ short Asl[128 * 40];
    __shared__ short Bsl[128 * 40];

    f4v acc[4][4] = {};

    for (int k0 = 0; k0 < K; k0 += 32) {
        // ---- stage A: rows m, K-contiguous ----
        for (int g = tid; g < 512; g += 256) {
            int r = g >> 2, kg = (g & 3) << 3;
            int gr = m0 + r, gk = k0 + kg;
            s8v val = {0, 0, 0, 0, 0, 0, 0, 0};
            if (gr < M) {
                const short* src = (const short*)A + (size_t)gr * lda + gk;
                if (gk + 8 <= K) val = *(const s8v*)src;
                else {
#pragma unroll
                    for (int j = 0; j < 8; ++j) if (gk + j < K) val[j] = src[j];
                }
            }
            *(s8v*)&Asl[r * 40 + kg] = val;
        }
        // ---- stage B ----
        if (TRB) {
            for (int g = tid; g < 512; g += 256) {
                int r = g >> 2, kg = (g & 3) << 3;
                int gr = n0 + r, gk = k0 + kg;
                s8v val = {0, 0, 0, 0, 0, 0, 0, 0};
                if (gr < N) {
                    const short* src = (const short*)B + (size_t)gr * ldb + gk;
                    if (gk + 8 <= K) val = *(const s8v*)src;
                    else {
#pragma unroll
                        for (int j = 0; j < 8; ++j) if (gk + j < K) val[j] = src[j];
                    }
                }
                *(s8v*)&Bsl[r * 40 + kg] = val;
            }
        } else {
            for (int g = tid; g < 512; g += 256) {
                int kr = g >> 4, ng = (g & 15) << 3;
                int gk = k0 + kr, gn = n0 + ng;
                s8v val = {0, 0, 0, 0, 0, 0, 0, 0};
                if (gk < K) {
                    const short* src = (const short*)B + (size_t)gk * ldb + gn;
                    if (gn + 8 <= N) val = *(const s8v*)src;
                    else {
#pragma unroll
                        for (int j = 0; j < 8; ++j) if (gn + j < N) val[j] = src[j];
                    }
                }
#pragma unroll
                for (int j = 0; j < 8; ++j) Bsl[(ng + j) * 40 + kr] = val[j];
            }
        }
        __syncthreads();
        // ---- compute ----
        b8v af[4], bfr[4];
#pragma unroll
        for (int mi = 0; mi < 4; ++mi)
            af[mi] = *(const b8v*)&Asl[(wm + mi * 16 + l16) * 40 + quad * 8];
#pragma unroll
        for (int ni = 0; ni < 4; ++ni)
            bfr[ni] = *(const b8v*)&Bsl[(wn + ni * 16 + l16) * 40 + quad * 8];
#pragma unroll
        for (int mi = 0; mi < 4; ++mi)
#pragma unroll
            for (int ni = 0; ni < 4; ++ni)
                acc[mi][ni] = __builtin_amdgcn_mfma_f32_16x16x32_bf16(af[mi], bfr[ni], acc[mi][ni], 0, 0, 0);
        __syncthreads();
    }

    // ---- epilogue ----
    bf16* Co = (bf16*)Cb;
    float* Cf = (float*)Cb;
#pragma unroll
    for (int mi = 0; mi < 4; ++mi) {
#pragma unroll
        for (int ni = 0; ni < 4; ++ni) {
            int gn = n0 + wn + ni * 16 + l16;
            float bv = 0.f;
            if (BIAS == 1 && gn < N) bv = tofl(bias[gn]);
#pragma unroll
            for (int r = 0; r < 4; ++r) {
                int gm = m0 + wm + mi * 16 + quad * 4 + r;
                if (gm < M && gn < N) {
                    float v = acc[mi][ni][r] + bv;
                    if (BIAS == 2) v += tofl(bias[gm]);
                    if (ACT == 1) v = gelu_f(v);
                    if (ACT == 2) v = v > 0.f ? v + 1.f : expf(v);
                    size_t ci = coff + (size_t)gm * ldc + gn;
                    if (OUT == 0) Co[ci] = f2b(v);
                    else if (OUT == 1) Cf[ci] = v;
                    else Cf[ci] += v;
                }
            }
        }
    }
}

// ---------------- attention micro-kernels ----------------
// per-chunk partial kv/ksum: chunk c covers t in [c*207, (c+1)*207)
__global__ __launch_bounds__(256) void kv_part(
    const bf16* __restrict__ Kf, const bf16* __restrict__ V,
    float* __restrict__ kvp, float* __restrict__ ksp)
{
    int bh = blockIdx.x, c = blockIdx.y;
    int b = bh >> 3, h = bh & 7;
    int tbase = c * CHLEN, tend = tbase + CHLEN;
    __shared__ float ks[32][64];
    __shared__ float vs[32][64];
    int tid = threadIdx.x;
    int e = tid >> 2, dg = tid & 3;
    f4v a0 = {}, a1 = {}, a2 = {}, a3 = {};
    float ksacc = 0.f;
    int srow = tid >> 3, sc = (tid & 7) << 3;
    for (int t0 = tbase; t0 < tend; t0 += 32) {
        int t = t0 + srow;
        s8v kk8 = {0, 0, 0, 0, 0, 0, 0, 0};
        s8v vv8 = {0, 0, 0, 0, 0, 0, 0, 0};
        if (t < tend) {
            size_t off2 = ((size_t)(b * cT + t)) * cD + h * cE + sc;
            kk8 = *(const s8v*)((const short*)Kf + off2);
            vv8 = *(const s8v*)((const short*)V + off2);
        }
        __syncthreads();   // previous compute done before overwrite
        f4v kf0, kf1, vf0, vf1;
#pragma unroll
        for (int j = 0; j < 4; ++j) {
            kf0[j] = b2f_raw(kk8[j]);     kf1[j] = b2f_raw(kk8[4 + j]);
            vf0[j] = b2f_raw(vv8[j]);     vf1[j] = b2f_raw(vv8[4 + j]);
        }
        *(f4v*)&ks[srow][sc] = kf0;  *(f4v*)&ks[srow][sc + 4] = kf1;
        *(f4v*)&vs[srow][sc] = vf0;  *(f4v*)&vs[srow][sc + 4] = vf1;
        __syncthreads();
#pragma unroll 8
        for (int tt = 0; tt < 32; ++tt) {
            float kf = ks[tt][e];
            ksacc += kf;
            const float* vp2 = &vs[tt][dg * 16];
            f4v v0 = *(const f4v*)(vp2);
            f4v v1 = *(const f4v*)(vp2 + 4);
            f4v v2 = *(const f4v*)(vp2 + 8);
            f4v v3 = *(const f4v*)(vp2 + 12);
            a0 += kf * v0;  a1 += kf * v1;  a2 += kf * v2;  a3 += kf * v3;
        }
    }
    size_t base = (((size_t)c * 64 + bh) * cE + e) * cE + dg * 16;
    *(f4v*)&kvp[base]      = a0;
    *(f4v*)&kvp[base + 4]  = a1;
    *(f4v*)&kvp[base + 8]  = a2;
    *(f4v*)&kvp[base + 12] = a3;
    if (dg == 0) ksp[(size_t)c * 4096 + bh * cE + e] = ksacc;
}

__global__ void kv_reduce(const float* __restrict__ kvp, const float* __restrict__ ksp,
                          float* __restrict__ kvf, float* __restrict__ ksf)
{
    size_t idx = (size_t)blockIdx.x * 256 + threadIdx.x;
    if (idx < 262144) {
        float s = 0.f;
#pragma unroll
        for (int c2 = 0; c2 < KVCH; ++c2) s += kvp[(size_t)c2 * 262144 + idx];
        kvf[idx] = s;
    } else if (idx < 262144 + 4096) {
        size_t i = idx - 262144;
        float s = 0.f;
#pragma unroll
        for (int c2 = 0; c2 < KVCH; ++c2) s += ksp[(size_t)c2 * 4096 + i];
        ksf[i] = s;
    }
}

// O = (q . kv) * 1/(q . ksum + eps)  via MFMA.
// grid (ceil(cT/256), 64 bh); block 256 = 4 waves; wave w computes 64 rows x 64 cols.
// A-fragments read directly from global Q (16B aligned); B = kv^T bf16 in LDS.
// Denominator fused as a 5th MFMA with ksum in column 0 of a B-fragment.
__global__ __launch_bounds__(256) void attn_o3(
    const bf16* __restrict__ Qf, const float* __restrict__ kv,
    const float* __restrict__ ksum, bf16* __restrict__ O)
{
    int c = blockIdx.x, bh = blockIdx.y;
    int b = bh >> 3, h = bh & 7;
    __shared__ short kvs[64 * 72];        // kvT[d'][e], rows padded to 72 (144B, 16B-aligned)
    int tid = threadIdx.x;
    const float* kvsrc = kv + (size_t)bh * 4096;
    for (int i = tid; i < 4096; i += 256) {
        int e = i >> 6, dp = i & 63;      // kvf[e][d'] -> kvs[d'][e]
        kvs[dp * 72 + e] = f2b_raw(kvsrc[i]);
    }
    int lane = tid & 63, w = tid >> 6;
    int l16 = lane & 15, quad = lane >> 4;

    // den B-fragment: B[k][0] = ksum[k], other cols 0
    b8v kd[2];
    short* kdp = (short*)kd;
#pragma unroll
    for (int kk = 0; kk < 2; ++kk)
#pragma unroll
        for (int j = 0; j < 8; ++j)
            kdp[kk * 8 + j] = (l16 == 0) ? f2b_raw(ksum[bh * 64 + kk * 32 + quad * 8 + j]) : (short)0;
    __syncthreads();

    int rbase = c * 256 + w * 64;
    const short* Qs = (const short*)Qf;
    f4v acc[4][4] = {};
    f4v aden[4] = {};
#pragma unroll
    for (int kk = 0; kk < 2; ++kk) {
        b8v bfr[4];
#pragma unroll
        for (int ni = 0; ni < 4; ++ni)
            bfr[ni] = *(const b8v*)&kvs[(ni * 16 + l16) * 72 + kk * 32 + quad * 8];
#pragma unroll
        for (int mi = 0; mi < 4; ++mi) {
            int grow = rbase + mi * 16 + l16;
            b8v af = {};
            if (grow < cT)
                af = *(const b8v*)(Qs + ((size_t)(b * cT + grow)) * cD + h * cE + kk * 32 + quad * 8);
#pragma unroll
            for (int ni = 0; ni < 4; ++ni)
                acc[mi][ni] = __builtin_amdgcn_mfma_f32_16x16x32_bf16(af, bfr[ni], acc[mi][ni], 0, 0, 0);
            aden[mi] = __builtin_amdgcn_mfma_f32_16x16x32_bf16(af, kd[kk], aden[mi], 0, 0, 0);
        }
    }

#pragma unroll
    for (int mi = 0; mi < 4; ++mi) {
#pragma unroll
        for (int r = 0; r < 4; ++r) {
            float den = __shfl(aden[mi][r], lane & 48);   // broadcast from col-0 lane of this quad
            float z = 1.f / (den + 1e-6f);
            int grow = rbase + mi * 16 + quad * 4 + r;
            if (grow < cT) {
                size_t base = ((size_t)(b * cT + grow)) * cD + h * cE;
#pragma unroll
                for (int ni = 0; ni < 4; ++ni)
                    O[base + ni * 16 + l16] = f2b(acc[mi][ni][r] * z);
            }
        }
    }
}

// out = LN(a + b) * g + be   (bf16 in/out; optional dynamic second write)
template <int DUAL>
__global__ __launch_bounds__(256) void add_ln(
    const bf16* __restrict__ a, const bf16* __restrict__ b,
    const bf16* __restrict__ g, const bf16* __restrict__ be,
    bf16* __restrict__ out, void* __restrict__ dyn_out,
    const int* __restrict__ fl, size_t dyn_off)
{
    int row = blockIdx.x;
    size_t base = (size_t)row * cD;
    int t = threadIdx.x;
    float x0 = tofl(a[base + t]) + tofl(b[base + t]);
    float x1 = tofl(a[base + t + 256]) + tofl(b[base + t + 256]);
    float s1 = x0 + x1, s2 = x0 * x0 + x1 * x1;
#pragma unroll
    for (int off = 32; off; off >>= 1) { s1 += __shfl_down(s1, off); s2 += __shfl_down(s2, off); }
    __shared__ float r1[4], r2[4];
    int w = t >> 6;
    if ((t & 63) == 0) { r1[w] = s1; r2[w] = s2; }
    __syncthreads();
    float S1 = r1[0] + r1[1] + r1[2] + r1[3];
    float S2 = r2[0] + r2[1] + r2[2] + r2[3];
    float mean = S1 * (1.f / cD);
    float var = S2 * (1.f / cD) - mean * mean;
    float inv = rsqrtf(var + 1e-5f);
    float y0 = (x0 - mean) * inv * tofl(g[t]) + tofl(be[t]);
    float y1 = (x1 - mean) * inv * tofl(g[t + 256]) + tofl(be[t + 256]);
    out[base + t] = f2b(y0);
    out[base + t + 256] = f2b(y1);
    if (DUAL) {
        int bf = *fl;
        stout(dyn_out, dyn_off + base + t, y0, bf);
        stout(dyn_out, dyn_off + base + t + 256, y1, bf);
    }
}

// XT[b,o,n,d] = sum_l ttw[o,l]*t_out[b,l,n,d] + ttb[o]   (8 d-elems per thread)
__global__ void tout2_kernel(const bf16* __restrict__ tout, const bf16* __restrict__ ttw,
                             const bf16* __restrict__ ttb, bf16* __restrict__ XT)
{
    size_t idx8 = ((size_t)blockIdx.x * 256 + threadIdx.x) * 8;
    if (idx8 >= SZ) return;
    int d = (int)(idx8 & (cD - 1));
    size_t r = idx8 >> 9;
    int n = (int)(r % cN);
    size_t r2 = r / cN;
    int o = (int)(r2 % cO);
    int b = (int)(r2 / cO);
    float tb = tofl(ttb[o]);
    float acc[8];
#pragma unroll
    for (int j = 0; j < 8; ++j) acc[j] = tb;
    size_t base = ((size_t)b * cT + n) * cD + d;
    const short* ts = (const short*)tout;
#pragma unroll
    for (int l = 0; l < cL; ++l) {
        float wv = tofl(ttw[o * cL + l]);
        s8v v = *(const s8v*)(ts + base + (size_t)l * cN * cD);
#pragma unroll
        for (int j = 0; j < 8; ++j) acc[j] += wv * b2f_raw(v[j]);
    }
    s8v ov;
#pragma unroll
    for (int j = 0; j < 8; ++j) ov[j] = f2b_raw(acc[j]);
    *(s8v*)((short*)XT + idx8) = ov;
}

// At3[s][m][n] = adj[n,m,s]  (row stride 208, bf16)
__global__ void extract_adjT(const void* __restrict__ adj, bf16* __restrict__ At3,
                             const int* __restrict__ fl)
{
    int bf = *fl;
    int idx = blockIdx.x * 256 + threadIdx.x;
    if (idx >= cNG * cN * cN) return;
    int s = idx / (cN * cN);
    int rem = idx - s * cN * cN;
    int m = rem / cN;
    int n = rem - m * cN;
    At3[((size_t)s * cN + m) * 208 + n] = f2b(ldin(adj, (size_t)(n * cN + m) * cNG + s, bf));
}

// dts[b,o,n,d] = (G + gb[o,d]) * bng[o,d] + bnb[o,d]
__global__ void dts_kernel(const float* __restrict__ g, const bf16* __restrict__ gb,
                           const bf16* __restrict__ bng, const bf16* __restrict__ bnb,
                           void* __restrict__ out, const int* __restrict__ fl)
{
    int bf = *fl;
    size_t idx = (size_t)blockIdx.x * 256 + threadIdx.x;
    if (idx >= SZ) return;
    int d = idx & (cD - 1);
    size_t r = idx >> 9;
    int o = (int)((r / cN) % cO);
    int od = o * cD + d;
    float v = (g[idx] + tofl(gb[od])) * tofl(bng[od]) + tofl(bnb[od]);
    stout(out, idx, v, bf);
}

// ---------------- host helpers ----------------
static inline dim3 g2(int M, int N, int bz) { return dim3((N + 127) / 128, (M + 127) / 128, bz); }

static void run_attn(const bf16* Aq, const bf16* Akv, const bf16* wT, const bf16* bias,
                     bf16* Q, bf16* K, bf16* V, bf16* outp,
                     float* kvp, float* ksp, float* kvf, float* ksf, hipStream_t s)
{
    mgemm_f<1, 2, 0><<<g2(cBT, cD, 1), 256, 0, s>>>(Aq,  wT,          Q, bias,          cBT, cD, cD, cD, cD, cD, 0, 0, 0, 1, 1, 0, 0);
    mgemm_f<1, 2, 0><<<g2(cBT, cD, 1), 256, 0, s>>>(Akv, wT + DD,     K, bias + cD,     cBT, cD, cD, cD, cD, cD, 0, 0, 0, 1, 1, 0, 0);
    mgemm_f<1, 0, 0><<<g2(cBT, cD, 1), 256, 0, s>>>(Akv, wT + 2 * DD, V, bias + 2 * cD, cBT, cD, cD, cD, cD, cD, 0, 0, 0, 1, 1, 0, 0);
    kv_part<<<dim3(64, KVCH), 256, 0, s>>>(K, V, kvp, ksp);
    kv_reduce<<<1040, 256, 0, s>>>(kvp, ksp, kvf, ksf);
    attn_o3<<<dim3((cT + 255) / 256, 64), 256, 0, s>>>(Q, kvf, ksf, Q);
    mgemm_f<1, 0, 0><<<g2(cBT, cD, 1), 256, 0, s>>>(Q, wT + 3 * DD, outp, bias + 3 * cD, cBT, cD, cD, cD, cD, cD, 0, 0, 0, 1, 1, 0, 0);
}

static void run_ffn(const bf16* inp, const bf16* w1T, const bf16* b1,
                    const bf16* w2T, const bf16* b2, bf16* mid, bf16* outp, hipStream_t s)
{
    const int MH = cBT / 2;
    for (int h = 0; h < 2; ++h) {
        const bf16* ip = inp + (size_t)h * MH * cD;
        bf16* op = outp + (size_t)h * MH * cD;
        mgemm_f<1, 1, 0><<<g2(MH, cF, 1), 256, 0, s>>>(ip, w1T, mid, b1, MH, cF, cD, cD, cD, cF, 0, 0, 0, 1, 1, 0, 0);
        mgemm_f<1, 0, 0><<<g2(MH, cD, 1), 256, 0, s>>>(mid, w2T, op, b2, MH, cD, cF, cF, cF, cD, 0, 0, 0, 1, 1, 0, 0);
    }
}

// ---------------- entry point ----------------
extern "C" void kernel_launch(void* const* d_in, const int* in_sizes, int n_in,
                              void* d_out, int out_size, void* d_ws, size_t ws_size,
                              hipStream_t stream)
{
    const void* x    = d_in[0];
    const void* st   = d_in[1];
    const void* adj  = d_in[3];
    const void* eqw  = d_in[4];
    const void* eqb  = d_in[5];
    const void* ew1  = d_in[6];
    const void* eb1  = d_in[7];
    const void* ew2  = d_in[8];
    const void* eb2  = d_in[9];
    const void* elng = d_in[10];
    const void* elnb = d_in[11];
    const void* dsw  = d_in[12];
    const void* dsb  = d_in[13];
    const void* dcw  = d_in[14];
    const void* dcb  = d_in[15];
    const void* dw1  = d_in[16];
    const void* db1  = d_in[17];
    const void* dw2  = d_in[18];
    const void* db2  = d_in[19];
    const void* dlng = d_in[20];
    const void* dlnb = d_in[21];
    const void* ttw  = d_in[22];
    const void* ttb  = d_in[23];
    const void* tsw  = d_in[24];
    const void* tsb  = d_in[25];
    const void* gw   = d_in[26];
    const void* gb   = d_in[27];
    const void* bng  = d_in[28];
    const void* bnb  = d_in[29];

    bf16* P = (bf16*)d_ws;
    size_t off = 0;
    auto alloc = [&](size_t n) { size_t o = off; off += (n + 127) & ~(size_t)127; return o; };

    size_t eqwT = alloc(4 * DD);
    size_t dswT = alloc(4 * DD);
    size_t dcwT = alloc(4 * DD);
    size_t ew1T = alloc((size_t)cD * cF);
    size_t ew2T = alloc((size_t)cD * cF);
    size_t dw1T = alloc((size_t)cD * cF);
    size_t dw2T = alloc((size_t)cD * cF);
    size_t gwB  = alloc((size_t)cO * cD * 4608);
    size_t tswB = alloc((size_t)cN * cD);
    size_t xb   = alloc(SZ);
    size_t stb  = alloc(SZ);
    size_t eqbB = alloc(4 * cD), eb1B = alloc(cF), eb2B = alloc(cD);
    size_t elngB = alloc(2 * cD), elnbB = alloc(2 * cD);
    size_t dsbB = alloc(4 * cD), dcbB = alloc(4 * cD);
    size_t db1B = alloc(cF), db2B = alloc(cD);
    size_t dlngB = alloc(3 * cD), dlnbB = alloc(3 * cD);
    size_t ttwB = alloc(cO * cL), ttbB = alloc(cO), tsbB = alloc(cN);
    size_t gbB = alloc(cO * cD), bngB = alloc(cO * cD), bnbB = alloc(cO * cD);
    size_t at3 = alloc((size_t)cNG * cN * 208);
    size_t slots = alloc(6 * SZ);
    bf16* S[6];
    for (int i = 0; i < 6; ++i) S[i] = P + slots + (size_t)i * SZ;

    float* F0  = (float*)(P + off);
    float* kvp = F0;                              // KVCH*64*64*64
    float* ksp = kvp + (size_t)KVCH * 262144;     // KVCH*4096
    float* kvf = ksp + (size_t)KVCH * 4096;       // 64*64*64
    float* ksf = kvf + 262144;                    // 4096
    int* flag  = (int*)(ksf + 4096);

    detect_kernel<<<1, 256, 0, stream>>>(x, flag);

    // ---- converts ----
    for (int i = 0; i < 4; ++i) {
        cvt_tr<<<1024, 256, 0, stream>>>(P + eqwT + i * DD, eqw, flag, cD, cD, (size_t)i * DD);
        cvt_tr<<<1024, 256, 0, stream>>>(P + dswT + i * DD, dsw, flag, cD, cD, (size_t)i * DD);
        cvt_tr<<<1024, 256, 0, stream>>>(P + dcwT + i * DD, dcw, flag, cD, cD, (size_t)i * DD);
    }
    cvt_tr<<<4096, 256, 0, stream>>>(P + ew1T, ew1, flag, cD, cF, 0);
    cvt_tr<<<4096, 256, 0, stream>>>(P + ew2T, ew2, flag, cF, cD, 0);
    cvt_tr<<<4096, 256, 0, stream>>>(P + dw1T, dw1, flag, cD, cF, 0);
    cvt_tr<<<4096, 256, 0, stream>>>(P + dw2T, dw2, flag, cF, cD, 0);
    cvt_copy<<<27648, 256, 0, stream>>>(P + gwB, gw, flag, (size_t)cO * cD * 4608, 0);
    cvt_copy<<<104, 256, 0, stream>>>(P + tswB, tsw, flag, (size_t)cN * cD, 0);
    cvt_copy<<<(int)((SZ + 1023) / 1024), 256, 0, stream>>>(P + xb, x, flag, SZ, 0);
    cvt_copy<<<(int)((SZ + 1023) / 1024), 256, 0, stream>>>(P + stb, st, flag, SZ, 0);
    cvt_copy<<<2, 256, 0, stream>>>(P + eqbB, eqb, flag, 4 * cD, 0);
    cvt_copy<<<2, 256, 0, stream>>>(P + eb1B, eb1, flag, cF, 0);
    cvt_copy<<<1, 256, 0, stream>>>(P + eb2B, eb2, flag, cD, 0);
    cvt_copy<<<1, 256, 0, stream>>>(P + elngB, elng, flag, 2 * cD, 0);
    cvt_copy<<<1, 256, 0, stream>>>(P + elnbB, elnb, flag, 2 * cD, 0);
    cvt_copy<<<2, 256, 0, stream>>>(P + dsbB, dsb, flag, 4 * cD, 0);
    cvt_copy<<<2, 256, 0, stream>>>(P + dcbB, dcb, flag, 4 * cD, 0);
    cvt_copy<<<2, 256, 0, stream>>>(P + db1B, db1, flag, cF, 0);
    cvt_copy<<<1, 256, 0, stream>>>(P + db2B, db2, flag, cD, 0);
    cvt_copy<<<2, 256, 0, stream>>>(P + dlngB, dlng, flag, 3 * cD, 0);
    cvt_copy<<<2, 256, 0, stream>>>(P + dlnbB, dlnb, flag, 3 * cD, 0);
    cvt_copy<<<1, 256, 0, stream>>>(P + ttwB, ttw, flag, cO * cL, 0);
    cvt_copy<<<1, 256, 0, stream>>>(P + ttbB, ttb, flag, cO, 0);
    cvt_copy<<<1, 256, 0, stream>>>(P + tsbB, tsb, flag, cN, 0);
    cvt_copy<<<6, 256, 0, stream>>>(P + gbB, gb, flag, cO * cD, 0);
    cvt_copy<<<6, 256, 0, stream>>>(P + bngB, bng, flag, cO * cD, 0);
    cvt_copy<<<6, 256, 0, stream>>>(P + bnbB, bnb, flag, cO * cD, 0);

    // ===== encoder =====
    run_attn(P + xb, P + xb, P + eqwT, P + eqbB, S[0], S[1], S[2], S[3], kvp, ksp, kvf, ksf, stream);
    add_ln<0><<<cBT, 256, 0, stream>>>(P + xb, S[3], P + elngB, P + elnbB, S[4], nullptr, flag, 0);   // y
    run_ffn(S[4], P + ew1T, P + eb1B, P + ew2T, P + eb2B, S[0], S[2], stream);
    add_ln<0><<<cBT, 256, 0, stream>>>(S[4], S[2], P + elngB + cD, P + elnbB + cD, S[5], nullptr, flag, 0);  // t_out

    // ===== decoder self-attn =====
    run_attn(P + stb, P + stb, P + dswT, P + dsbB, S[0], S[1], S[2], S[3], kvp, ksp, kvf, ksf, stream);
    add_ln<0><<<cBT, 256, 0, stream>>>(P + stb, S[3], P + dlngB, P + dlnbB, S[4], nullptr, flag, 0);  // q1

    // ===== decoder cross-attn (Q from q1, KV from t_out) =====
    run_attn(S[4], S[5], P + dcwT, P + dcbB, S[0], S[1], S[2], S[3], kvp, ksp, kvf, ksf, stream);
    add_ln<0><<<cBT, 256, 0, stream>>>(S[4], S[3], P + dlngB + cD, P + dlnbB + cD, S[4], nullptr, flag, 0);  // q2 (in-place)

    // ===== decoder FFN + s_out =====
    run_ffn(S[4], P + dw1T, P + db1B, P + dw2T, P + db2B, S[0], S[2], stream);
    add_ln<1><<<cBT, 256, 0, stream>>>(S[4], S[2], P + dlngB + 2 * cD, P + dlnbB + 2 * cD, S[3], d_out, flag, SZ);

    // ===== temporal projection X_T -> S0 =====
    tout2_kernel<<<(int)(SZ / 2048), 256, 0, stream>>>(S[5], P + ttwB, P + ttbB, S[0]);

    // ===== adaptive adjacency AadT[bz][m][n] (ldc=208) -> S1 =====
    mgemm_f<2, 0, 0><<<g2(cN, cN, cB * cO), 256, 0, stream>>>(
        P + tswB, S[3], S[1], P + tsbB, cN, cN, cD, cD, cD, 208,
        0, (long)cN * cD, (long)cN * 208, 1, 0, 0, 0);

    extract_adjT<<<(cNG * cN * cN + 255) / 256, 256, 0, stream>>>(adj, P + at3, flag);

    // ===== graph diffusion + GCN =====
    float* G = (float*)S[4];           // S4+S5 = SZ floats

    auto accum = [&](const bf16* Feat, int f) {
        mgemm_f<0, 0, 2><<<g2(cN, cD, cB * cO), 256, 0, stream>>>(
            Feat, P + gwB, G, nullptr, cN, cD, cD, cD, 4608, cD,
            (long)cN * cD, (long)cD * 4608, (long)cN * cD, 0, cO, 0, (long)f * cD);
    };
    auto featmul = [&](const bf16* A, long sA, int modA, long aoff0, const bf16* Fin, bf16* Fout) {
        mgemm<false, 0, 0, 0><<<g2(cN, cD, cB * cO), 256, 0, stream>>>(
            A, Fin, Fout, nullptr, cN, cD, cN, 208, cD, cD,
            sA, (long)cN * cD, (long)cN * cD, modA, 0, aoff0, 0);
    };

    // first accumulate WRITES G (OUT=1) -> no zerof pass needed
    mgemm_f<0, 0, 1><<<g2(cN, cD, cB * cO), 256, 0, stream>>>(
        S[0], P + gwB, G, nullptr, cN, cD, cD, cD, 4608, cD,
        (long)cN * cD, (long)cD * 4608, (long)cN * cD, 0, cO, 0, 0);
    for (int s = 0; s < cNG; ++s) {
        featmul(P + at3, 0, 1, (long)s * cN * 208, S[0], S[3]);
        accum(S[3], 2 * s + 1);
        featmul(P + at3, 0, 1, (long)s * cN * 208, S[3], S[2]);
        accum(S[2], 2 * s + 2);
    }
    featmul(S[1], (long)cN * 208, 0, 0, S[0], S[3]);
    accum(S[3], 7);
    featmul(S[1], (long)cN * 208, 0, 0, S[3], S[2]);
    accum(S[2], 8);

    // ===== epilogue =====
    dts_kernel<<<(int)((SZ + 255) / 256), 256, 0, stream>>>(G, P + gbB, P + bngB, P + bnbB, d_out, flag);
}

// Round 5
// 2196.349 us; speedup vs baseline: 1.2454x; 1.0504x over previous
//
#include <hip/hip_runtime.h>
#include <hip/hip_bf16.h>
#include <cstddef>

using bf16 = __hip_bfloat16;
typedef short s8v __attribute__((ext_vector_type(8)));
typedef __bf16 b8v __attribute__((ext_vector_type(8)));
typedef float f4v __attribute__((ext_vector_type(4)));

// ---------------- problem constants ----------------
constexpr int cB = 8, cL = 12, cN = 207, cD = 512, cH = 8, cF = 2048;
constexpr int cO = 12, cNG = 3;
constexpr int cT  = cL * cN;          // 2484
constexpr int cBT = cB * cT;          // 19872
constexpr int cE  = cD / cH;          // 64
constexpr size_t SZ = (size_t)cBT * cD;   // 10,174,464
constexpr long DD = (long)cD * cD;    // 262144
constexpr int KVCH = 12;              // kv_part chunks (2484 = 12*207)
constexpr int CHLEN = 207;

// ---------------- helpers ----------------
__device__ __forceinline__ float tofl(bf16 v) { return __bfloat162float(v); }
__device__ __forceinline__ bf16 f2b(float v) { return __float2bfloat16(v); }
__device__ __forceinline__ float b2f_raw(short s) {
    unsigned u = ((unsigned)(unsigned short)s) << 16;
    float f; __builtin_memcpy(&f, &u, 4); return f;
}
__device__ __forceinline__ short f2b_raw(float v) {
    bf16 t = __float2bfloat16(v);
    short s; __builtin_memcpy(&s, &t, 2); return s;
}
__device__ __forceinline__ float ldin(const void* p, size_t i, int bf) {
    return bf ? __bfloat162float(((const bf16*)p)[i]) : ((const float*)p)[i];
}
__device__ __forceinline__ void stout(void* p, size_t i, float v, int bf) {
    if (bf) ((bf16*)p)[i] = f2b(v);
    else    ((float*)p)[i] = v;
}
__device__ __forceinline__ float gelu_f(float x) {
    float x3 = x * x * x;
    return 0.5f * x * (1.f + tanhf(0.7978845608028654f * (x + 0.044715f * x3)));
}
// async global->LDS, 16B per lane; lds must be wave-uniform base (HW adds lane*16)
__device__ __forceinline__ void gload16(void* lds, const void* g) {
    __builtin_amdgcn_global_load_lds(
        (const __attribute__((address_space(1))) unsigned int*)g,
        (__attribute__((address_space(3))) unsigned int*)lds,
        16, 0, 0);
}

// ---------------- dtype detection ----------------
__global__ void detect_kernel(const void* __restrict__ x, int* __restrict__ flag) {
    __shared__ float red[4];
    int t = threadIdx.x;
    float m = 0.f;
    for (int i = t; i < 1024; i += 256) {
        float v = __bfloat162float(((const bf16*)x)[i]);
        if (v != v) v = 1e30f;
        m = fmaxf(m, fabsf(v));
    }
#pragma unroll
    for (int off = 32; off; off >>= 1) m = fmaxf(m, __shfl_down(m, off));
    if ((t & 63) == 0) red[t >> 6] = m;
    __syncthreads();
    if (t == 0) {
        float mm = fmaxf(fmaxf(red[0], red[1]), fmaxf(red[2], red[3]));
        flag[0] = (mm < 1e3f) ? 1 : 0;
    }
}

// ---------------- convert kernels ----------------
__global__ void cvt_copy(bf16* __restrict__ dst, const void* __restrict__ src,
                         const int* __restrict__ fl, size_t n, size_t soff) {
    int bf = *fl;
#pragma unroll
    for (int j = 0; j < 4; ++j) {
        size_t i = (size_t)blockIdx.x * 1024 + (size_t)j * 256 + threadIdx.x;
        if (i < n) dst[i] = f2b(ldin(src, soff + i, bf));
    }
}
// dst[n*K + k] = src[soff + k*N + n]
__global__ void cvt_tr(bf16* __restrict__ dst, const void* __restrict__ src,
                       const int* __restrict__ fl, int K, int N, size_t soff) {
    int bf = *fl;
    size_t idx = (size_t)blockIdx.x * 256 + threadIdx.x;
    if (idx >= (size_t)K * N) return;
    int n = (int)(idx / K), k = (int)(idx % K);
    dst[idx] = f2b(ldin(src, soff + (size_t)k * N + n, bf));
}

// ---------------- bijective XCD swizzle (m204) ----------------
__device__ __forceinline__ void xcd_swz(unsigned& bx, unsigned& by, unsigned& bz) {
    unsigned gx = gridDim.x, gy = gridDim.y;
    unsigned nwg = gx * gy * gridDim.z;
    unsigned orig = (blockIdx.z * gy + blockIdx.y) * gx + blockIdx.x;
    unsigned q = nwg >> 3, r = nwg & 7;
    unsigned xcd = orig & 7, sub = orig >> 3;
    unsigned wg = (xcd < r ? xcd * (q + 1) : r * (q + 1) + (xcd - r) * q) + sub;
    bx = wg % gx;
    unsigned t1 = wg / gx;
    by = t1 % gy;
    bz = t1 / gy;
}

// ---------------- fast MFMA GEMM (TRB=true only, K%32==0) ----------------
// C[bz](MxN) = A[bz](MxK,row-major) @ B^T ; B row-major NxK
// m97 structure + T3 minimal 2-phase: double-buffered LDS, stage(k+1) issued
// BEFORE compute(k) so the compute phase hides load latency; ONE barrier/iter.
// OUT: 0=bf16 store, 1=f32 store, 2=f32 +=
template <int BIAS, int ACT, int OUT>
__global__ __launch_bounds__(256) void mgemm_f(
    const bf16* __restrict__ Ab, const bf16* __restrict__ Bb, void* __restrict__ Cb,
    const bf16* __restrict__ bias,
    int M, int N, int K, int lda, int ldb, int ldc,
    long sA, long sB, long sC, int modA, int modB, long aoff0, long boff0)
{
    unsigned bxu, byu, bzu;
    xcd_swz(bxu, byu, bzu);
    int bz = (int)bzu;
    const bf16* A = Ab + aoff0 + (size_t)(modA ? (bz % modA) : bz) * sA;
    const bf16* B = Bb + boff0 + (size_t)(modB ? (bz % modB) : bz) * sB;
    size_t coff = (size_t)bz * sC;

    int m0 = (int)byu * 128, n0 = (int)bxu * 128;
    int tid = threadIdx.x;
    int lane = tid & 63, w = tid >> 6;
    int wm = (w & 1) * 64, wn = (w >> 1) * 64;
    int l16 = lane & 15, quad = lane >> 4;

    __shared__ short As[2][128 * 32];   // double-buffered, linear [row][k], 64B rows
    __shared__ short Bs[2][128 * 32];

    // staging geometry: thread t covers row t/4 (+64 for pass 1), k-col (t%4)*8
    int srow = tid >> 2, scol = (tid & 3) << 3;
    int ar0 = m0 + srow;      if (ar0 >= M) ar0 = M - 1;   // clamp: garbage rows never stored
    int ar1 = m0 + srow + 64; if (ar1 >= M) ar1 = M - 1;
    int br0 = n0 + srow;      if (br0 >= N) br0 = N - 1;
    int br1 = n0 + srow + 64; if (br1 >= N) br1 = N - 1;
    const bf16* ap0 = A + (size_t)ar0 * lda + scol;
    const bf16* ap1 = A + (size_t)ar1 * lda + scol;
    const bf16* bp0 = B + (size_t)br0 * ldb + scol;
    const bf16* bp1 = B + (size_t)br1 * ldb + scol;

    f4v acc[4][4] = {};

    auto stage = [&](int buf) {
        gload16(&As[buf][w * 512], ap0);          // wave-uniform LDS bases
        gload16(&As[buf][2048 + w * 512], ap1);
        gload16(&Bs[buf][w * 512], bp0);
        gload16(&Bs[buf][2048 + w * 512], bp1);
        ap0 += 32; ap1 += 32; bp0 += 32; bp1 += 32;
    };
    auto compute = [&](int buf) {
        b8v af[4], bfr[4];
#pragma unroll
        for (int mi = 0; mi < 4; ++mi)
            af[mi] = *(const b8v*)&As[buf][(wm + mi * 16 + l16) * 32 + quad * 8];
#pragma unroll
        for (int ni = 0; ni < 4; ++ni)
            bfr[ni] = *(const b8v*)&Bs[buf][(wn + ni * 16 + l16) * 32 + quad * 8];
#pragma unroll
        for (int mi = 0; mi < 4; ++mi)
#pragma unroll
            for (int ni = 0; ni < 4; ++ni)
                acc[mi][ni] = __builtin_amdgcn_mfma_f32_16x16x32_bf16(af[mi], bfr[ni], acc[mi][ni], 0, 0, 0);
    };

    int nk = K >> 5;
    stage(0);
    __syncthreads();                   // drains vmcnt: buf0 ready for all waves
    int cur = 0;
    for (int kk = 0; kk < nk - 1; ++kk) {
        stage(cur ^ 1);                // issue next tile's loads FIRST
        compute(cur);                  // ds_read+MFMA hide the load latency
        __syncthreads();               // residual vmcnt drain + buffer handoff
        cur ^= 1;
    }
    compute(cur);                      // last tile: no prefetch

    // ---- epilogue ----
    bf16* Co = (bf16*)Cb;
    float* Cf = (float*)Cb;
#pragma unroll
    for (int mi = 0; mi < 4; ++mi) {
#pragma unroll
        for (int ni = 0; ni < 4; ++ni) {
            int gn = n0 + wn + ni * 16 + l16;
            float bv = 0.f;
            if (BIAS == 1 && gn < N) bv = tofl(bias[gn]);
#pragma unroll
            for (int r = 0; r < 4; ++r) {
                int gm = m0 + wm + mi * 16 + quad * 4 + r;
                if (gm < M && gn < N) {
                    float v = acc[mi][ni][r] + bv;
                    if (BIAS == 2) v += tofl(bias[gm]);
                    if (ACT == 1) v = gelu_f(v);
                    if (ACT == 2) v = v > 0.f ? v + 1.f : expf(v);
                    size_t ci = coff + (size_t)gm * ldc + gn;
                    if (OUT == 0) Co[ci] = f2b(v);
                    else if (OUT == 1) Cf[ci] = v;
                    else Cf[ci] += v;
                }
            }
        }
    }
}

// ---------------- generic MFMA GEMM (kept for TRB=false / K%32!=0) ----------------
template <bool TRB, int BIAS, int ACT, int OUT>
__global__ __launch_bounds__(256) void mgemm(
    const bf16* __restrict__ Ab, const bf16* __restrict__ Bb, void* __restrict__ Cb,
    const bf16* __restrict__ bias,
    int M, int N, int K, int lda, int ldb, int ldc,
    long sA, long sB, long sC, int modA, int modB, long aoff0, long boff0)
{
    unsigned bxu, byu, bzu;
    xcd_swz(bxu, byu, bzu);
    int bz = (int)bzu;
    const bf16* A = Ab + aoff0 + (size_t)(modA ? (bz % modA) : bz) * sA;
    const bf16* B = Bb + boff0 + (size_t)(modB ? (bz % modB) : bz) * sB;
    size_t coff = (size_t)bz * sC;

    int m0 = (int)byu * 128, n0 = (int)bxu * 128;
    int tid = threadIdx.x;
    int lane = tid & 63, w = tid >> 6;
    int wm = (w & 1) * 64, wn = (w >> 1) * 64;
    int l16 = lane & 15, quad = lane >> 4;

    __shared__ short Asl[128 * 40];
    __shared__ short Bsl[128 * 40];

    f4v acc[4][4] = {};

    for (int k0 = 0; k0 < K; k0 += 32) {
        // ---- stage A: rows m, K-contiguous ----
        for (int g = tid; g < 512; g += 256) {
            int r = g >> 2, kg = (g & 3) << 3;
            int gr = m0 + r, gk = k0 + kg;
            s8v val = {0, 0, 0, 0, 0, 0, 0, 0};
            if (gr < M) {
                const short* src = (const short*)A + (size_t)gr * lda + gk;
                if (gk + 8 <= K) val = *(const s8v*)src;
                else {
#pragma unroll
                    for (int j = 0; j < 8; ++j) if (gk + j < K) val[j] = src[j];
                }
            }
            *(s8v*)&Asl[r * 40 + kg] = val;
        }
        // ---- stage B ----
        if (TRB) {
            for (int g = tid; g < 512; g += 256) {
                int r = g >> 2, kg = (g & 3) << 3;
                int gr = n0 + r, gk = k0 + kg;
                s8v val = {0, 0, 0, 0, 0, 0, 0, 0};
                if (gr < N) {
                    const short* src = (const short*)B + (size_t)gr * ldb + gk;
                    if (gk + 8 <= K) val = *(const s8v*)src;
                    else {
#pragma unroll
                        for (int j = 0; j < 8; ++j) if (gk + j < K) val[j] = src[j];
                    }
                }
                *(s8v*)&Bsl[r * 40 + kg] = val;
            }
        } else {
            for (int g = tid; g < 512; g += 256) {
                int kr = g >> 4, ng = (g & 15) << 3;
                int gk = k0 + kr, gn = n0 + ng;
                s8v val = {0, 0, 0, 0, 0, 0, 0, 0};
                if (gk < K) {
                    const short* src = (const short*)B + (size_t)gk * ldb + gn;
                    if (gn + 8 <= N) val = *(const s8v*)src;
                    else {
#pragma unroll
                        for (int j = 0; j < 8; ++j) if (gn + j < N) val[j] = src[j];
                    }
                }
#pragma unroll
                for (int j = 0; j < 8; ++j) Bsl[(ng + j) * 40 + kr] = val[j];
            }
        }
        __syncthreads();
        // ---- compute ----
        b8v af[4], bfr[4];
#pragma unroll
        for (int mi = 0; mi < 4; ++mi)
            af[mi] = *(const b8v*)&Asl[(wm + mi * 16 + l16) * 40 + quad * 8];
#pragma unroll
        for (int ni = 0; ni < 4; ++ni)
            bfr[ni] = *(const b8v*)&Bsl[(wn + ni * 16 + l16) * 40 + quad * 8];
#pragma unroll
        for (int mi = 0; mi < 4; ++mi)
#pragma unroll
            for (int ni = 0; ni < 4; ++ni)
                acc[mi][ni] = __builtin_amdgcn_mfma_f32_16x16x32_bf16(af[mi], bfr[ni], acc[mi][ni], 0, 0, 0);
        __syncthreads();
    }

    // ---- epilogue ----
    bf16* Co = (bf16*)Cb;
    float* Cf = (float*)Cb;
#pragma unroll
    for (int mi = 0; mi < 4; ++mi) {
#pragma unroll
        for (int ni = 0; ni < 4; ++ni) {
            int gn = n0 + wn + ni * 16 + l16;
            float bv = 0.f;
            if (BIAS == 1 && gn < N) bv = tofl(bias[gn]);
#pragma unroll
            for (int r = 0; r < 4; ++r) {
                int gm = m0 + wm + mi * 16 + quad * 4 + r;
                if (gm < M && gn < N) {
                    float v = acc[mi][ni][r] + bv;
                    if (BIAS == 2) v += tofl(bias[gm]);
                    if (ACT == 1) v = gelu_f(v);
                    if (ACT == 2) v = v > 0.f ? v + 1.f : expf(v);
                    size_t ci = coff + (size_t)gm * ldc + gn;
                    if (OUT == 0) Co[ci] = f2b(v);
                    else if (OUT == 1) Cf[ci] = v;
                    else Cf[ci] += v;
                }
            }
        }
    }
}

// ---------------- attention micro-kernels ----------------
// per-chunk partial kv/ksum: chunk c covers t in [c*207, (c+1)*207)
__global__ __launch_bounds__(256) void kv_part(
    const bf16* __restrict__ Kf, const bf16* __restrict__ V,
    float* __restrict__ kvp, float* __restrict__ ksp)
{
    int bh = blockIdx.x, c = blockIdx.y;
    int b = bh >> 3, h = bh & 7;
    int tbase = c * CHLEN, tend = tbase + CHLEN;
    __shared__ float ks[32][64];
    __shared__ float vs[32][64];
    int tid = threadIdx.x;
    int e = tid >> 2, dg = tid & 3;
    f4v a0 = {}, a1 = {}, a2 = {}, a3 = {};
    float ksacc = 0.f;
    int srow = tid >> 3, sc = (tid & 7) << 3;
    for (int t0 = tbase; t0 < tend; t0 += 32) {
        int t = t0 + srow;
        s8v kk8 = {0, 0, 0, 0, 0, 0, 0, 0};
        s8v vv8 = {0, 0, 0, 0, 0, 0, 0, 0};
        if (t < tend) {
            size_t off2 = ((size_t)(b * cT + t)) * cD + h * cE + sc;
            kk8 = *(const s8v*)((const short*)Kf + off2);
            vv8 = *(const s8v*)((const short*)V + off2);
        }
        __syncthreads();   // previous compute done before overwrite
        f4v kf0, kf1, vf0, vf1;
#pragma unroll
        for (int j = 0; j < 4; ++j) {
            kf0[j] = b2f_raw(kk8[j]);     kf1[j] = b2f_raw(kk8[4 + j]);
            vf0[j] = b2f_raw(vv8[j]);     vf1[j] = b2f_raw(vv8[4 + j]);
        }
        *(f4v*)&ks[srow][sc] = kf0;  *(f4v*)&ks[srow][sc + 4] = kf1;
        *(f4v*)&vs[srow][sc] = vf0;  *(f4v*)&vs[srow][sc + 4] = vf1;
        __syncthreads();
#pragma unroll 8
        for (int tt = 0; tt < 32; ++tt) {
            float kf = ks[tt][e];
            ksacc += kf;
            const float* vp2 = &vs[tt][dg * 16];
            f4v v0 = *(const f4v*)(vp2);
            f4v v1 = *(const f4v*)(vp2 + 4);
            f4v v2 = *(const f4v*)(vp2 + 8);
            f4v v3 = *(const f4v*)(vp2 + 12);
            a0 += kf * v0;  a1 += kf * v1;  a2 += kf * v2;  a3 += kf * v3;
        }
    }
    size_t base = (((size_t)c * 64 + bh) * cE + e) * cE + dg * 16;
    *(f4v*)&kvp[base]      = a0;
    *(f4v*)&kvp[base + 4]  = a1;
    *(f4v*)&kvp[base + 8]  = a2;
    *(f4v*)&kvp[base + 12] = a3;
    if (dg == 0) ksp[(size_t)c * 4096 + bh * cE + e] = ksacc;
}

__global__ void kv_reduce(const float* __restrict__ kvp, const float* __restrict__ ksp,
                          float* __restrict__ kvf, float* __restrict__ ksf)
{
    size_t idx = (size_t)blockIdx.x * 256 + threadIdx.x;
    if (idx < 262144) {
        float s = 0.f;
#pragma unroll
        for (int c2 = 0; c2 < KVCH; ++c2) s += kvp[(size_t)c2 * 262144 + idx];
        kvf[idx] = s;
    } else if (idx < 262144 + 4096) {
        size_t i = idx - 262144;
        float s = 0.f;
#pragma unroll
        for (int c2 = 0; c2 < KVCH; ++c2) s += ksp[(size_t)c2 * 4096 + i];
        ksf[i] = s;
    }
}

// O = (q . kv) * 1/(q . ksum + eps)  via MFMA.
// grid (ceil(cT/256), 64 bh); block 256 = 4 waves; wave w computes 64 rows x 64 cols.
// A-fragments read directly from global Q (16B aligned); B = kv^T bf16 in LDS.
// Denominator fused as a 5th MFMA with ksum in column 0 of a B-fragment.
__global__ __launch_bounds__(256) void attn_o3(
    const bf16* __restrict__ Qf, const float* __restrict__ kv,
    const float* __restrict__ ksum, bf16* __restrict__ O)
{
    int c = blockIdx.x, bh = blockIdx.y;
    int b = bh >> 3, h = bh & 7;
    __shared__ short kvs[64 * 72];        // kvT[d'][e], rows padded to 72 (144B, 16B-aligned)
    int tid = threadIdx.x;
    const float* kvsrc = kv + (size_t)bh * 4096;
    for (int i = tid; i < 4096; i += 256) {
        int e = i >> 6, dp = i & 63;      // kvf[e][d'] -> kvs[d'][e]
        kvs[dp * 72 + e] = f2b_raw(kvsrc[i]);
    }
    int lane = tid & 63, w = tid >> 6;
    int l16 = lane & 15, quad = lane >> 4;

    // den B-fragment: B[k][0] = ksum[k], other cols 0
    b8v kd[2];
    short* kdp = (short*)kd;
#pragma unroll
    for (int kk = 0; kk < 2; ++kk)
#pragma unroll
        for (int j = 0; j < 8; ++j)
            kdp[kk * 8 + j] = (l16 == 0) ? f2b_raw(ksum[bh * 64 + kk * 32 + quad * 8 + j]) : (short)0;
    __syncthreads();

    int rbase = c * 256 + w * 64;
    const short* Qs = (const short*)Qf;
    f4v acc[4][4] = {};
    f4v aden[4] = {};
#pragma unroll
    for (int kk = 0; kk < 2; ++kk) {
        b8v bfr[4];
#pragma unroll
        for (int ni = 0; ni < 4; ++ni)
            bfr[ni] = *(const b8v*)&kvs[(ni * 16 + l16) * 72 + kk * 32 + quad * 8];
#pragma unroll
        for (int mi = 0; mi < 4; ++mi) {
            int grow = rbase + mi * 16 + l16;
            b8v af = {};
            if (grow < cT)
                af = *(const b8v*)(Qs + ((size_t)(b * cT + grow)) * cD + h * cE + kk * 32 + quad * 8);
#pragma unroll
            for (int ni = 0; ni < 4; ++ni)
                acc[mi][ni] = __builtin_amdgcn_mfma_f32_16x16x32_bf16(af, bfr[ni], acc[mi][ni], 0, 0, 0);
            aden[mi] = __builtin_amdgcn_mfma_f32_16x16x32_bf16(af, kd[kk], aden[mi], 0, 0, 0);
        }
    }

#pragma unroll
    for (int mi = 0; mi < 4; ++mi) {
#pragma unroll
        for (int r = 0; r < 4; ++r) {
            float den = __shfl(aden[mi][r], lane & 48);   // broadcast from col-0 lane of this quad
            float z = 1.f / (den + 1e-6f);
            int grow = rbase + mi * 16 + quad * 4 + r;
            if (grow < cT) {
                size_t base = ((size_t)(b * cT + grow)) * cD + h * cE;
#pragma unroll
                for (int ni = 0; ni < 4; ++ni)
                    O[base + ni * 16 + l16] = f2b(acc[mi][ni][r] * z);
            }
        }
    }
}

// out = LN(a + b) * g + be   (bf16 in/out; optional dynamic second write)
template <int DUAL>
__global__ __launch_bounds__(256) void add_ln(
    const bf16* __restrict__ a, const bf16* __restrict__ b,
    const bf16* __restrict__ g, const bf16* __restrict__ be,
    bf16* __restrict__ out, void* __restrict__ dyn_out,
    const int* __restrict__ fl, size_t dyn_off)
{
    int row = blockIdx.x;
    size_t base = (size_t)row * cD;
    int t = threadIdx.x;
    float x0 = tofl(a[base + t]) + tofl(b[base + t]);
    float x1 = tofl(a[base + t + 256]) + tofl(b[base + t + 256]);
    float s1 = x0 + x1, s2 = x0 * x0 + x1 * x1;
#pragma unroll
    for (int off = 32; off; off >>= 1) { s1 += __shfl_down(s1, off); s2 += __shfl_down(s2, off); }
    __shared__ float r1[4], r2[4];
    int w = t >> 6;
    if ((t & 63) == 0) { r1[w] = s1; r2[w] = s2; }
    __syncthreads();
    float S1 = r1[0] + r1[1] + r1[2] + r1[3];
    float S2 = r2[0] + r2[1] + r2[2] + r2[3];
    float mean = S1 * (1.f / cD);
    float var = S2 * (1.f / cD) - mean * mean;
    float inv = rsqrtf(var + 1e-5f);
    float y0 = (x0 - mean) * inv * tofl(g[t]) + tofl(be[t]);
    float y1 = (x1 - mean) * inv * tofl(g[t + 256]) + tofl(be[t + 256]);
    out[base + t] = f2b(y0);
    out[base + t + 256] = f2b(y1);
    if (DUAL) {
        int bf = *fl;
        stout(dyn_out, dyn_off + base + t, y0, bf);
        stout(dyn_out, dyn_off + base + t + 256, y1, bf);
    }
}

// XT[b,o,n,d] = sum_l ttw[o,l]*t_out[b,l,n,d] + ttb[o]   (8 d-elems per thread)
__global__ void tout2_kernel(const bf16* __restrict__ tout, const bf16* __restrict__ ttw,
                             const bf16* __restrict__ ttb, bf16* __restrict__ XT)
{
    size_t idx8 = ((size_t)blockIdx.x * 256 + threadIdx.x) * 8;
    if (idx8 >= SZ) return;
    int d = (int)(idx8 & (cD - 1));
    size_t r = idx8 >> 9;
    int n = (int)(r % cN);
    size_t r2 = r / cN;
    int o = (int)(r2 % cO);
    int b = (int)(r2 / cO);
    float tb = tofl(ttb[o]);
    float acc[8];
#pragma unroll
    for (int j = 0; j < 8; ++j) acc[j] = tb;
    size_t base = ((size_t)b * cT + n) * cD + d;
    const short* ts = (const short*)tout;
#pragma unroll
    for (int l = 0; l < cL; ++l) {
        float wv = tofl(ttw[o * cL + l]);
        s8v v = *(const s8v*)(ts + base + (size_t)l * cN * cD);
#pragma unroll
        for (int j = 0; j < 8; ++j) acc[j] += wv * b2f_raw(v[j]);
    }
    s8v ov;
#pragma unroll
    for (int j = 0; j < 8; ++j) ov[j] = f2b_raw(acc[j]);
    *(s8v*)((short*)XT + idx8) = ov;
}

// At3[s][m][n] = adj[n,m,s]  (row stride 208, bf16)
__global__ void extract_adjT(const void* __restrict__ adj, bf16* __restrict__ At3,
                             const int* __restrict__ fl)
{
    int bf = *fl;
    int idx = blockIdx.x * 256 + threadIdx.x;
    if (idx >= cNG * cN * cN) return;
    int s = idx / (cN * cN);
    int rem = idx - s * cN * cN;
    int m = rem / cN;
    int n = rem - m * cN;
    At3[((size_t)s * cN + m) * 208 + n] = f2b(ldin(adj, (size_t)(n * cN + m) * cNG + s, bf));
}

// dts[b,o,n,d] = (G + gb[o,d]) * bng[o,d] + bnb[o,d]
__global__ void dts_kernel(const float* __restrict__ g, const bf16* __restrict__ gb,
                           const bf16* __restrict__ bng, const bf16* __restrict__ bnb,
                           void* __restrict__ out, const int* __restrict__ fl)
{
    int bf = *fl;
    size_t idx = (size_t)blockIdx.x * 256 + threadIdx.x;
    if (idx >= SZ) return;
    int d = idx & (cD - 1);
    size_t r = idx >> 9;
    int o = (int)((r / cN) % cO);
    int od = o * cD + d;
    float v = (g[idx] + tofl(gb[od])) * tofl(bng[od]) + tofl(bnb[od]);
    stout(out, idx, v, bf);
}

// ---------------- host helpers ----------------
static inline dim3 g2(int M, int N, int bz) { return dim3((N + 127) / 128, (M + 127) / 128, bz); }

static void run_attn(const bf16* Aq, const bf16* Akv, const bf16* wT, const bf16* bias,
                     bf16* Q, bf16* K, bf16* V, bf16* outp,
                     float* kvp, float* ksp, float* kvf, float* ksf, hipStream_t s)
{
    mgemm_f<1, 2, 0><<<g2(cBT, cD, 1), 256, 0, s>>>(Aq,  wT,          Q, bias,          cBT, cD, cD, cD, cD, cD, 0, 0, 0, 1, 1, 0, 0);
    mgemm_f<1, 2, 0><<<g2(cBT, cD, 1), 256, 0, s>>>(Akv, wT + DD,     K, bias + cD,     cBT, cD, cD, cD, cD, cD, 0, 0, 0, 1, 1, 0, 0);
    mgemm_f<1, 0, 0><<<g2(cBT, cD, 1), 256, 0, s>>>(Akv, wT + 2 * DD, V, bias + 2 * cD, cBT, cD, cD, cD, cD, cD, 0, 0, 0, 1, 1, 0, 0);
    kv_part<<<dim3(64, KVCH), 256, 0, s>>>(K, V, kvp, ksp);
    kv_reduce<<<1040, 256, 0, s>>>(kvp, ksp, kvf, ksf);
    attn_o3<<<dim3((cT + 255) / 256, 64), 256, 0, s>>>(Q, kvf, ksf, Q);
    mgemm_f<1, 0, 0><<<g2(cBT, cD, 1), 256, 0, s>>>(Q, wT + 3 * DD, outp, bias + 3 * cD, cBT, cD, cD, cD, cD, cD, 0, 0, 0, 1, 1, 0, 0);
}

static void run_ffn(const bf16* inp, const bf16* w1T, const bf16* b1,
                    const bf16* w2T, const bf16* b2, bf16* mid, bf16* outp, hipStream_t s)
{
    const int MH = cBT / 2;
    for (int h = 0; h < 2; ++h) {
        const bf16* ip = inp + (size_t)h * MH * cD;
        bf16* op = outp + (size_t)h * MH * cD;
        mgemm_f<1, 1, 0><<<g2(MH, cF, 1), 256, 0, s>>>(ip, w1T, mid, b1, MH, cF, cD, cD, cD, cF, 0, 0, 0, 1, 1, 0, 0);
        mgemm_f<1, 0, 0><<<g2(MH, cD, 1), 256, 0, s>>>(mid, w2T, op, b2, MH, cD, cF, cF, cF, cD, 0, 0, 0, 1, 1, 0, 0);
    }
}

// ---------------- entry point ----------------
extern "C" void kernel_launch(void* const* d_in, const int* in_sizes, int n_in,
                              void* d_out, int out_size, void* d_ws, size_t ws_size,
                              hipStream_t stream)
{
    const void* x    = d_in[0];
    const void* st   = d_in[1];
    const void* adj  = d_in[3];
    const void* eqw  = d_in[4];
    const void* eqb  = d_in[5];
    const void* ew1  = d_in[6];
    const void* eb1  = d_in[7];
    const void* ew2  = d_in[8];
    const void* eb2  = d_in[9];
    const void* elng = d_in[10];
    const void* elnb = d_in[11];
    const void* dsw  = d_in[12];
    const void* dsb  = d_in[13];
    const void* dcw  = d_in[14];
    const void* dcb  = d_in[15];
    const void* dw1  = d_in[16];
    const void* db1  = d_in[17];
    const void* dw2  = d_in[18];
    const void* db2  = d_in[19];
    const void* dlng = d_in[20];
    const void* dlnb = d_in[21];
    const void* ttw  = d_in[22];
    const void* ttb  = d_in[23];
    const void* tsw  = d_in[24];
    const void* tsb  = d_in[25];
    const void* gw   = d_in[26];
    const void* gb   = d_in[27];
    const void* bng  = d_in[28];
    const void* bnb  = d_in[29];

    bf16* P = (bf16*)d_ws;
    size_t off = 0;
    auto alloc = [&](size_t n) { size_t o = off; off += (n + 127) & ~(size_t)127; return o; };

    size_t eqwT = alloc(4 * DD);
    size_t dswT = alloc(4 * DD);
    size_t dcwT = alloc(4 * DD);
    size_t ew1T = alloc((size_t)cD * cF);
    size_t ew2T = alloc((size_t)cD * cF);
    size_t dw1T = alloc((size_t)cD * cF);
    size_t dw2T = alloc((size_t)cD * cF);
    size_t gwB  = alloc((size_t)cO * cD * 4608);
    size_t tswB = alloc((size_t)cN * cD);
    size_t xb   = alloc(SZ);
    size_t stb  = alloc(SZ);
    size_t eqbB = alloc(4 * cD), eb1B = alloc(cF), eb2B = alloc(cD);
    size_t elngB = alloc(2 * cD), elnbB = alloc(2 * cD);
    size_t dsbB = alloc(4 * cD), dcbB = alloc(4 * cD);
    size_t db1B = alloc(cF), db2B = alloc(cD);
    size_t dlngB = alloc(3 * cD), dlnbB = alloc(3 * cD);
    size_t ttwB = alloc(cO * cL), ttbB = alloc(cO), tsbB = alloc(cN);
    size_t gbB = alloc(cO * cD), bngB = alloc(cO * cD), bnbB = alloc(cO * cD);
    size_t at3 = alloc((size_t)cNG * cN * 208);
    size_t slots = alloc(6 * SZ);
    bf16* S[6];
    for (int i = 0; i < 6; ++i) S[i] = P + slots + (size_t)i * SZ;

    float* F0  = (float*)(P + off);
    float* kvp = F0;                              // KVCH*64*64*64
    float* ksp = kvp + (size_t)KVCH * 262144;     // KVCH*4096
    float* kvf = ksp + (size_t)KVCH * 4096;       // 64*64*64
    float* ksf = kvf + 262144;                    // 4096
    int* flag  = (int*)(ksf + 4096);

    detect_kernel<<<1, 256, 0, stream>>>(x, flag);

    // ---- converts ----
    for (int i = 0; i < 4; ++i) {
        cvt_tr<<<1024, 256, 0, stream>>>(P + eqwT + i * DD, eqw, flag, cD, cD, (size_t)i * DD);
        cvt_tr<<<1024, 256, 0, stream>>>(P + dswT + i * DD, dsw, flag, cD, cD, (size_t)i * DD);
        cvt_tr<<<1024, 256, 0, stream>>>(P + dcwT + i * DD, dcw, flag, cD, cD, (size_t)i * DD);
    }
    cvt_tr<<<4096, 256, 0, stream>>>(P + ew1T, ew1, flag, cD, cF, 0);
    cvt_tr<<<4096, 256, 0, stream>>>(P + ew2T, ew2, flag, cF, cD, 0);
    cvt_tr<<<4096, 256, 0, stream>>>(P + dw1T, dw1, flag, cD, cF, 0);
    cvt_tr<<<4096, 256, 0, stream>>>(P + dw2T, dw2, flag, cF, cD, 0);
    cvt_copy<<<27648, 256, 0, stream>>>(P + gwB, gw, flag, (size_t)cO * cD * 4608, 0);
    cvt_copy<<<104, 256, 0, stream>>>(P + tswB, tsw, flag, (size_t)cN * cD, 0);
    cvt_copy<<<(int)((SZ + 1023) / 1024), 256, 0, stream>>>(P + xb, x, flag, SZ, 0);
    cvt_copy<<<(int)((SZ + 1023) / 1024), 256, 0, stream>>>(P + stb, st, flag, SZ, 0);
    cvt_copy<<<2, 256, 0, stream>>>(P + eqbB, eqb, flag, 4 * cD, 0);
    cvt_copy<<<2, 256, 0, stream>>>(P + eb1B, eb1, flag, cF, 0);
    cvt_copy<<<1, 256, 0, stream>>>(P + eb2B, eb2, flag, cD, 0);
    cvt_copy<<<1, 256, 0, stream>>>(P + elngB, elng, flag, 2 * cD, 0);
    cvt_copy<<<1, 256, 0, stream>>>(P + elnbB, elnb, flag, 2 * cD, 0);
    cvt_copy<<<2, 256, 0, stream>>>(P + dsbB, dsb, flag, 4 * cD, 0);
    cvt_copy<<<2, 256, 0, stream>>>(P + dcbB, dcb, flag, 4 * cD, 0);
    cvt_copy<<<2, 256, 0, stream>>>(P + db1B, db1, flag, cF, 0);
    cvt_copy<<<1, 256, 0, stream>>>(P + db2B, db2, flag, cD, 0);
    cvt_copy<<<2, 256, 0, stream>>>(P + dlngB, dlng, flag, 3 * cD, 0);
    cvt_copy<<<2, 256, 0, stream>>>(P + dlnbB, dlnb, flag, 3 * cD, 0);
    cvt_copy<<<1, 256, 0, stream>>>(P + ttwB, ttw, flag, cO * cL, 0);
    cvt_copy<<<1, 256, 0, stream>>>(P + ttbB, ttb, flag, cO, 0);
    cvt_copy<<<1, 256, 0, stream>>>(P + tsbB, tsb, flag, cN, 0);
    cvt_copy<<<6, 256, 0, stream>>>(P + gbB, gb, flag, cO * cD, 0);
    cvt_copy<<<6, 256, 0, stream>>>(P + bngB, bng, flag, cO * cD, 0);
    cvt_copy<<<6, 256, 0, stream>>>(P + bnbB, bnb, flag, cO * cD, 0);

    // ===== encoder =====
    run_attn(P + xb, P + xb, P + eqwT, P + eqbB, S[0], S[1], S[2], S[3], kvp, ksp, kvf, ksf, stream);
    add_ln<0><<<cBT, 256, 0, stream>>>(P + xb, S[3], P + elngB, P + elnbB, S[4], nullptr, flag, 0);   // y
    run_ffn(S[4], P + ew1T, P + eb1B, P + ew2T, P + eb2B, S[0], S[2], stream);
    add_ln<0><<<cBT, 256, 0, stream>>>(S[4], S[2], P + elngB + cD, P + elnbB + cD, S[5], nullptr, flag, 0);  // t_out

    // ===== decoder self-attn =====
    run_attn(P + stb, P + stb, P + dswT, P + dsbB, S[0], S[1], S[2], S[3], kvp, ksp, kvf, ksf, stream);
    add_ln<0><<<cBT, 256, 0, stream>>>(P + stb, S[3], P + dlngB, P + dlnbB, S[4], nullptr, flag, 0);  // q1

    // ===== decoder cross-attn (Q from q1, KV from t_out) =====
    run_attn(S[4], S[5], P + dcwT, P + dcbB, S[0], S[1], S[2], S[3], kvp, ksp, kvf, ksf, stream);
    add_ln<0><<<cBT, 256, 0, stream>>>(S[4], S[3], P + dlngB + cD, P + dlnbB + cD, S[4], nullptr, flag, 0);  // q2 (in-place)

    // ===== decoder FFN + s_out =====
    run_ffn(S[4], P + dw1T, P + db1B, P + dw2T, P + db2B, S[0], S[2], stream);
    add_ln<1><<<cBT, 256, 0, stream>>>(S[4], S[2], P + dlngB + 2 * cD, P + dlnbB + 2 * cD, S[3], d_out, flag, SZ);

    // ===== temporal projection X_T -> S0 =====
    tout2_kernel<<<(int)(SZ / 2048), 256, 0, stream>>>(S[5], P + ttwB, P + ttbB, S[0]);

    // ===== adaptive adjacency AadT[bz][m][n] (ldc=208) -> S1 =====
    mgemm_f<2, 0, 0><<<g2(cN, cN, cB * cO), 256, 0, stream>>>(
        P + tswB, S[3], S[1], P + tsbB, cN, cN, cD, cD, cD, 208,
        0, (long)cN * cD, (long)cN * 208, 1, 0, 0, 0);

    extract_adjT<<<(cNG * cN * cN + 255) / 256, 256, 0, stream>>>(adj, P + at3, flag);

    // ===== graph diffusion + GCN =====
    float* G = (float*)S[4];           // S4+S5 = SZ floats

    auto accum = [&](const bf16* Feat, int f) {
        mgemm_f<0, 0, 2><<<g2(cN, cD, cB * cO), 256, 0, stream>>>(
            Feat, P + gwB, G, nullptr, cN, cD, cD, cD, 4608, cD,
            (long)cN * cD, (long)cD * 4608, (long)cN * cD, 0, cO, 0, (long)f * cD);
    };
    auto featmul = [&](const bf16* A, long sA, int modA, long aoff0, const bf16* Fin, bf16* Fout) {
        mgemm<false, 0, 0, 0><<<g2(cN, cD, cB * cO), 256, 0, stream>>>(
            A, Fin, Fout, nullptr, cN, cD, cN, 208, cD, cD,
            sA, (long)cN * cD, (long)cN * cD, modA, 0, aoff0, 0);
    };

    // first accumulate WRITES G (OUT=1) -> no zerof pass needed
    mgemm_f<0, 0, 1><<<g2(cN, cD, cB * cO), 256, 0, stream>>>(
        S[0], P + gwB, G, nullptr, cN, cD, cD, cD, 4608, cD,
        (long)cN * cD, (long)cD * 4608, (long)cN * cD, 0, cO, 0, 0);
    for (int s = 0; s < cNG; ++s) {
        featmul(P + at3, 0, 1, (long)s * cN * 208, S[0], S[3]);
        accum(S[3], 2 * s + 1);
        featmul(P + at3, 0, 1, (long)s * cN * 208, S[3], S[2]);
        accum(S[2], 2 * s + 2);
    }
    featmul(S[1], (long)cN * 208, 0, 0, S[0], S[3]);
    accum(S[3], 7);
    featmul(S[1], (long)cN * 208, 0, 0, S[3], S[2]);
    accum(S[2], 8);

    // ===== epilogue =====
    dts_kernel<<<(int)((SZ + 255) / 256), 256, 0, stream>>>(G, P + gbB, P + bngB, P + bnbB, d_out, flag);
}

// Round 6
// 2185.248 us; speedup vs baseline: 1.2517x; 1.0051x over previous
//
#include <hip/hip_runtime.h>
#include <hip/hip_bf16.h>
#include <cstddef>

using bf16 = __hip_bfloat16;
typedef short s8v __attribute__((ext_vector_type(8)));
typedef __bf16 b8v __attribute__((ext_vector_type(8)));
typedef float f4v __attribute__((ext_vector_type(4)));

// ---------------- problem constants ----------------
constexpr int cB = 8, cL = 12, cN = 207, cD = 512, cH = 8, cF = 2048;
constexpr int cO = 12, cNG = 3;
constexpr int cT  = cL * cN;          // 2484
constexpr int cBT = cB * cT;          // 19872
constexpr int cE  = cD / cH;          // 64
constexpr size_t SZ = (size_t)cBT * cD;   // 10,174,464
constexpr long DD = (long)cD * cD;    // 262144
constexpr int KVCH = 12;              // kv_part chunks (2484 = 12*207)
constexpr int CHLEN = 207;

// ---------------- helpers ----------------
__device__ __forceinline__ float tofl(bf16 v) { return __bfloat162float(v); }
__device__ __forceinline__ bf16 f2b(float v) { return __float2bfloat16(v); }
__device__ __forceinline__ float b2f_raw(short s) {
    unsigned u = ((unsigned)(unsigned short)s) << 16;
    float f; __builtin_memcpy(&f, &u, 4); return f;
}
__device__ __forceinline__ short f2b_raw(float v) {
    bf16 t = __float2bfloat16(v);
    short s; __builtin_memcpy(&s, &t, 2); return s;
}
__device__ __forceinline__ float ldin(const void* p, size_t i, int bf) {
    return bf ? __bfloat162float(((const bf16*)p)[i]) : ((const float*)p)[i];
}
__device__ __forceinline__ void stout(void* p, size_t i, float v, int bf) {
    if (bf) ((bf16*)p)[i] = f2b(v);
    else    ((float*)p)[i] = v;
}
__device__ __forceinline__ float gelu_f(float x) {
    float x3 = x * x * x;
    return 0.5f * x * (1.f + tanhf(0.7978845608028654f * (x + 0.044715f * x3)));
}
// async global->LDS, 16B per lane; lds must be wave-uniform base (HW adds lane*16)
__device__ __forceinline__ void gload16(void* lds, const void* g) {
    __builtin_amdgcn_global_load_lds(
        (const __attribute__((address_space(1))) unsigned int*)g,
        (__attribute__((address_space(3))) unsigned int*)lds,
        16, 0, 0);
}

// ---------------- dtype detection ----------------
__global__ void detect_kernel(const void* __restrict__ x, int* __restrict__ flag) {
    __shared__ float red[4];
    int t = threadIdx.x;
    float m = 0.f;
    for (int i = t; i < 1024; i += 256) {
        float v = __bfloat162float(((const bf16*)x)[i]);
        if (v != v) v = 1e30f;
        m = fmaxf(m, fabsf(v));
    }
#pragma unroll
    for (int off = 32; off; off >>= 1) m = fmaxf(m, __shfl_down(m, off));
    if ((t & 63) == 0) red[t >> 6] = m;
    __syncthreads();
    if (t == 0) {
        float mm = fmaxf(fmaxf(red[0], red[1]), fmaxf(red[2], red[3]));
        flag[0] = (mm < 1e3f) ? 1 : 0;
    }
}

// ---------------- convert kernels (vectorized) ----------------
// 8 elems/thread; bf16 input path is a raw 16B vector copy.
__global__ void cvt_copy8(bf16* __restrict__ dst, const void* __restrict__ src,
                          const int* __restrict__ fl, size_t n, size_t soff) {
    int bf = *fl;
    size_t i8 = ((size_t)blockIdx.x * 256 + threadIdx.x) * 8;
    if (i8 + 8 <= n) {
        s8v ov;
        if (bf) {
            ov = *(const s8v*)((const short*)src + soff + i8);
        } else {
            const float* fs = (const float*)src + soff + i8;
            f4v a = *(const f4v*)fs;
            f4v b = *(const f4v*)(fs + 4);
#pragma unroll
            for (int j = 0; j < 4; ++j) { ov[j] = f2b_raw(a[j]); ov[4 + j] = f2b_raw(b[j]); }
        }
        *(s8v*)((short*)dst + i8) = ov;
    } else {
        for (size_t i = i8; i < n; ++i) dst[i] = f2b(ldin(src, soff + i, bf));
    }
}

// LDS tile transpose: dst[n*K + k] = src[soff + k*N + n].  REQUIRES K%64==0, N%64==0.
// grid (K/64, N/64); block 256. Coalesced reads AND writes; LDS stride 65 -> no conflicts.
__global__ void cvt_trt(bf16* __restrict__ dst, const void* __restrict__ src,
                        const int* __restrict__ fl, int K, int N, size_t soff) {
    int bf = *fl;
    int k0 = blockIdx.x * 64, n0 = blockIdx.y * 64;
    __shared__ float ts[64][65];
    int tid = threadIdx.x;
    int c = tid & 63, r0 = (tid >> 6) * 16;
#pragma unroll
    for (int j = 0; j < 16; ++j) {
        int r = r0 + j;
        ts[r][c] = ldin(src, soff + (size_t)(k0 + r) * N + n0 + c, bf);
    }
    __syncthreads();
#pragma unroll
    for (int j = 0; j < 16; ++j) {
        int rn = r0 + j;
        dst[(size_t)(n0 + rn) * K + k0 + c] = f2b(ts[c][rn]);
    }
}

// ---------------- bijective XCD swizzle (m204) ----------------
__device__ __forceinline__ void xcd_swz(unsigned& bx, unsigned& by, unsigned& bz) {
    unsigned gx = gridDim.x, gy = gridDim.y;
    unsigned nwg = gx * gy * gridDim.z;
    unsigned orig = (blockIdx.z * gy + blockIdx.y) * gx + blockIdx.x;
    unsigned q = nwg >> 3, r = nwg & 7;
    unsigned xcd = orig & 7, sub = orig >> 3;
    unsigned wg = (xcd < r ? xcd * (q + 1) : r * (q + 1) + (xcd - r) * q) + sub;
    bx = wg % gx;
    unsigned t1 = wg / gx;
    by = t1 % gy;
    bz = t1 / gy;
}

// ---------------- fast MFMA GEMM (TRB=true only, K%32==0) ----------------
// C[bz](MxN) = A[bz](MxK,row-major) @ B^T ; B row-major NxK
// m97 structure + T3 minimal 2-phase: double-buffered LDS, stage(k+1) issued
// BEFORE compute(k) so the compute phase hides load latency; ONE barrier/iter.
// OUT: 0=bf16 store, 1=f32 store, 2=f32 +=
template <int BIAS, int ACT, int OUT>
__global__ __launch_bounds__(256) void mgemm_f(
    const bf16* __restrict__ Ab, const bf16* __restrict__ Bb, void* __restrict__ Cb,
    const bf16* __restrict__ bias,
    int M, int N, int K, int lda, int ldb, int ldc,
    long sA, long sB, long sC, int modA, int modB, long aoff0, long boff0)
{
    unsigned bxu, byu, bzu;
    xcd_swz(bxu, byu, bzu);
    int bz = (int)bzu;
    const bf16* A = Ab + aoff0 + (size_t)(modA ? (bz % modA) : bz) * sA;
    const bf16* B = Bb + boff0 + (size_t)(modB ? (bz % modB) : bz) * sB;
    size_t coff = (size_t)bz * sC;

    int m0 = (int)byu * 128, n0 = (int)bxu * 128;
    int tid = threadIdx.x;
    int lane = tid & 63, w = tid >> 6;
    int wm = (w & 1) * 64, wn = (w >> 1) * 64;
    int l16 = lane & 15, quad = lane >> 4;

    __shared__ short As[2][128 * 32];   // double-buffered, linear [row][k], 64B rows
    __shared__ short Bs[2][128 * 32];

    // staging geometry: thread t covers row t/4 (+64 for pass 1), k-col (t%4)*8
    int srow = tid >> 2, scol = (tid & 3) << 3;
    int ar0 = m0 + srow;      if (ar0 >= M) ar0 = M - 1;   // clamp: garbage rows never stored
    int ar1 = m0 + srow + 64; if (ar1 >= M) ar1 = M - 1;
    int br0 = n0 + srow;      if (br0 >= N) br0 = N - 1;
    int br1 = n0 + srow + 64; if (br1 >= N) br1 = N - 1;
    const bf16* ap0 = A + (size_t)ar0 * lda + scol;
    const bf16* ap1 = A + (size_t)ar1 * lda + scol;
    const bf16* bp0 = B + (size_t)br0 * ldb + scol;
    const bf16* bp1 = B + (size_t)br1 * ldb + scol;

    f4v acc[4][4] = {};

    auto stage = [&](int buf) {
        gload16(&As[buf][w * 512], ap0);          // wave-uniform LDS bases
        gload16(&As[buf][2048 + w * 512], ap1);
        gload16(&Bs[buf][w * 512], bp0);
        gload16(&Bs[buf][2048 + w * 512], bp1);
        ap0 += 32; ap1 += 32; bp0 += 32; bp1 += 32;
    };
    auto compute = [&](int buf) {
        b8v af[4], bfr[4];
#pragma unroll
        for (int mi = 0; mi < 4; ++mi)
            af[mi] = *(const b8v*)&As[buf][(wm + mi * 16 + l16) * 32 + quad * 8];
#pragma unroll
        for (int ni = 0; ni < 4; ++ni)
            bfr[ni] = *(const b8v*)&Bs[buf][(wn + ni * 16 + l16) * 32 + quad * 8];
#pragma unroll
        for (int mi = 0; mi < 4; ++mi)
#pragma unroll
            for (int ni = 0; ni < 4; ++ni)
                acc[mi][ni] = __builtin_amdgcn_mfma_f32_16x16x32_bf16(af[mi], bfr[ni], acc[mi][ni], 0, 0, 0);
    };

    int nk = K >> 5;
    stage(0);
    __syncthreads();                   // drains vmcnt: buf0 ready for all waves
    int cur = 0;
    for (int kk = 0; kk < nk - 1; ++kk) {
        stage(cur ^ 1);                // issue next tile's loads FIRST
        compute(cur);                  // ds_read+MFMA hide the load latency
        __syncthreads();               // residual vmcnt drain + buffer handoff
        cur ^= 1;
    }
    compute(cur);                      // last tile: no prefetch

    // ---- epilogue ----
    bf16* Co = (bf16*)Cb;
    float* Cf = (float*)Cb;
#pragma unroll
    for (int mi = 0; mi < 4; ++mi) {
#pragma unroll
        for (int ni = 0; ni < 4; ++ni) {
            int gn = n0 + wn + ni * 16 + l16;
            float bv = 0.f;
            if (BIAS == 1 && gn < N) bv = tofl(bias[gn]);
#pragma unroll
            for (int r = 0; r < 4; ++r) {
                int gm = m0 + wm + mi * 16 + quad * 4 + r;
                if (gm < M && gn < N) {
                    float v = acc[mi][ni][r] + bv;
                    if (BIAS == 2) v += tofl(bias[gm]);
                    if (ACT == 1) v = gelu_f(v);
                    if (ACT == 2) v = v > 0.f ? v + 1.f : expf(v);
                    size_t ci = coff + (size_t)gm * ldc + gn;
                    if (OUT == 0) Co[ci] = f2b(v);
                    else if (OUT == 1) Cf[ci] = v;
                    else Cf[ci] += v;
                }
            }
        }
    }
}

// ---------------- generic MFMA GEMM (kept for TRB=false / K%32!=0) ----------------
template <bool TRB, int BIAS, int ACT, int OUT>
__global__ __launch_bounds__(256) void mgemm(
    const bf16* __restrict__ Ab, const bf16* __restrict__ Bb, void* __restrict__ Cb,
    const bf16* __restrict__ bias,
    int M, int N, int K, int lda, int ldb, int ldc,
    long sA, long sB, long sC, int modA, int modB, long aoff0, long boff0)
{
    unsigned bxu, byu, bzu;
    xcd_swz(bxu, byu, bzu);
    int bz = (int)bzu;
    const bf16* A = Ab + aoff0 + (size_t)(modA ? (bz % modA) : bz) * sA;
    const bf16* B = Bb + boff0 + (size_t)(modB ? (bz % modB) : bz) * sB;
    size_t coff = (size_t)bz * sC;

    int m0 = (int)byu * 128, n0 = (int)bxu * 128;
    int tid = threadIdx.x;
    int lane = tid & 63, w = tid >> 6;
    int wm = (w & 1) * 64, wn = (w >> 1) * 64;
    int l16 = lane & 15, quad = lane >> 4;

    __shared__ short Asl[128 * 40];
    __shared__ short Bsl[128 * 40];

    f4v acc[4][4] = {};

    for (int k0 = 0; k0 < K; k0 += 32) {
        // ---- stage A: rows m, K-contiguous ----
        for (int g = tid; g < 512; g += 256) {
            int r = g >> 2, kg = (g & 3) << 3;
            int gr = m0 + r, gk = k0 + kg;
            s8v val = {0, 0, 0, 0, 0, 0, 0, 0};
            if (gr < M) {
                const short* src = (const short*)A + (size_t)gr * lda + gk;
                if (gk + 8 <= K) val = *(const s8v*)src;
                else {
#pragma unroll
                    for (int j = 0; j < 8; ++j) if (gk + j < K) val[j] = src[j];
                }
            }
            *(s8v*)&Asl[r * 40 + kg] = val;
        }
        // ---- stage B ----
        if (TRB) {
            for (int g = tid; g < 512; g += 256) {
                int r = g >> 2, kg = (g & 3) << 3;
                int gr = n0 + r, gk = k0 + kg;
                s8v val = {0, 0, 0, 0, 0, 0, 0, 0};
                if (gr < N) {
                    const short* src = (const short*)B + (size_t)gr * ldb + gk;
                    if (gk + 8 <= K) val = *(const s8v*)src;
                    else {
#pragma unroll
                        for (int j = 0; j < 8; ++j) if (gk + j < K) val[j] = src[j];
                    }
                }
                *(s8v*)&Bsl[r * 40 + kg] = val;
            }
        } else {
            for (int g = tid; g < 512; g += 256) {
                int kr = g >> 4, ng = (g & 15) << 3;
                int gk = k0 + kr, gn = n0 + ng;
                s8v val = {0, 0, 0, 0, 0, 0, 0, 0};
                if (gk < K) {
                    const short* src = (const short*)B + (size_t)gk * ldb + gn;
                    if (gn + 8 <= N) val = *(const s8v*)src;
                    else {
#pragma unroll
                        for (int j = 0; j < 8; ++j) if (gn + j < N) val[j] = src[j];
                    }
                }
#pragma unroll
                for (int j = 0; j < 8; ++j) Bsl[(ng + j) * 40 + kr] = val[j];
            }
        }
        __syncthreads();
        // ---- compute ----
        b8v af[4], bfr[4];
#pragma unroll
        for (int mi = 0; mi < 4; ++mi)
            af[mi] = *(const b8v*)&Asl[(wm + mi * 16 + l16) * 40 + quad * 8];
#pragma unroll
        for (int ni = 0; ni < 4; ++ni)
            bfr[ni] = *(const b8v*)&Bsl[(wn + ni * 16 + l16) * 40 + quad * 8];
#pragma unroll
        for (int mi = 0; mi < 4; ++mi)
#pragma unroll
            for (int ni = 0; ni < 4; ++ni)
                acc[mi][ni] = __builtin_amdgcn_mfma_f32_16x16x32_bf16(af[mi], bfr[ni], acc[mi][ni], 0, 0, 0);
        __syncthreads();
    }

    // ---- epilogue ----
    bf16* Co = (bf16*)Cb;
    float* Cf = (float*)Cb;
#pragma unroll
    for (int mi = 0; mi < 4; ++mi) {
#pragma unroll
        for (int ni = 0; ni < 4; ++ni) {
            int gn = n0 + wn + ni * 16 + l16;
            float bv = 0.f;
            if (BIAS == 1 && gn < N) bv = tofl(bias[gn]);
#pragma unroll
            for (int r = 0; r < 4; ++r) {
                int gm = m0 + wm + mi * 16 + quad * 4 + r;
                if (gm < M && gn < N) {
                    float v = acc[mi][ni][r] + bv;
                    if (BIAS == 2) v += tofl(bias[gm]);
                    if (ACT == 1) v = gelu_f(v);
                    if (ACT == 2) v = v > 0.f ? v + 1.f : expf(v);
                    size_t ci = coff + (size_t)gm * ldc + gn;
                    if (OUT == 0) Co[ci] = f2b(v);
                    else if (OUT == 1) Cf[ci] = v;
                    else Cf[ci] += v;
                }
            }
        }
    }
}

// ---------------- attention micro-kernels ----------------
// per-chunk partial kv/ksum: chunk c covers t in [c*207, (c+1)*207)
__global__ __launch_bounds__(256) void kv_part(
    const bf16* __restrict__ Kf, const bf16* __restrict__ V,
    float* __restrict__ kvp, float* __restrict__ ksp)
{
    int bh = blockIdx.x, c = blockIdx.y;
    int b = bh >> 3, h = bh & 7;
    int tbase = c * CHLEN, tend = tbase + CHLEN;
    __shared__ float ks[32][64];
    __shared__ float vs[32][64];
    int tid = threadIdx.x;
    int e = tid >> 2, dg = tid & 3;
    f4v a0 = {}, a1 = {}, a2 = {}, a3 = {};
    float ksacc = 0.f;
    int srow = tid >> 3, sc = (tid & 7) << 3;
    for (int t0 = tbase; t0 < tend; t0 += 32) {
        int t = t0 + srow;
        s8v kk8 = {0, 0, 0, 0, 0, 0, 0, 0};
        s8v vv8 = {0, 0, 0, 0, 0, 0, 0, 0};
        if (t < tend) {
            size_t off2 = ((size_t)(b * cT + t)) * cD + h * cE + sc;
            kk8 = *(const s8v*)((const short*)Kf + off2);
            vv8 = *(const s8v*)((const short*)V + off2);
        }
        __syncthreads();   // previous compute done before overwrite
        f4v kf0, kf1, vf0, vf1;
#pragma unroll
        for (int j = 0; j < 4; ++j) {
            kf0[j] = b2f_raw(kk8[j]);     kf1[j] = b2f_raw(kk8[4 + j]);
            vf0[j] = b2f_raw(vv8[j]);     vf1[j] = b2f_raw(vv8[4 + j]);
        }
        *(f4v*)&ks[srow][sc] = kf0;  *(f4v*)&ks[srow][sc + 4] = kf1;
        *(f4v*)&vs[srow][sc] = vf0;  *(f4v*)&vs[srow][sc + 4] = vf1;
        __syncthreads();
#pragma unroll 8
        for (int tt = 0; tt < 32; ++tt) {
            float kf = ks[tt][e];
            ksacc += kf;
            const float* vp2 = &vs[tt][dg * 16];
            f4v v0 = *(const f4v*)(vp2);
            f4v v1 = *(const f4v*)(vp2 + 4);
            f4v v2 = *(const f4v*)(vp2 + 8);
            f4v v3 = *(const f4v*)(vp2 + 12);
            a0 += kf * v0;  a1 += kf * v1;  a2 += kf * v2;  a3 += kf * v3;
        }
    }
    size_t base = (((size_t)c * 64 + bh) * cE + e) * cE + dg * 16;
    *(f4v*)&kvp[base]      = a0;
    *(f4v*)&kvp[base + 4]  = a1;
    *(f4v*)&kvp[base + 8]  = a2;
    *(f4v*)&kvp[base + 12] = a3;
    if (dg == 0) ksp[(size_t)c * 4096 + bh * cE + e] = ksacc;
}

__global__ void kv_reduce(const float* __restrict__ kvp, const float* __restrict__ ksp,
                          float* __restrict__ kvf, float* __restrict__ ksf)
{
    size_t idx = (size_t)blockIdx.x * 256 + threadIdx.x;
    if (idx < 262144) {
        float s = 0.f;
#pragma unroll
        for (int c2 = 0; c2 < KVCH; ++c2) s += kvp[(size_t)c2 * 262144 + idx];
        kvf[idx] = s;
    } else if (idx < 262144 + 4096) {
        size_t i = idx - 262144;
        float s = 0.f;
#pragma unroll
        for (int c2 = 0; c2 < KVCH; ++c2) s += ksp[(size_t)c2 * 4096 + i];
        ksf[i] = s;
    }
}

// O = (q . kv) * 1/(q . ksum + eps)  via MFMA.
// grid (ceil(cT/256), 64 bh); block 256 = 4 waves; wave w computes 64 rows x 64 cols.
// A-fragments read directly from global Q (16B aligned); B = kv^T bf16 in LDS.
// Denominator fused as a 5th MFMA with ksum in column 0 of a B-fragment.
__global__ __launch_bounds__(256) void attn_o3(
    const bf16* __restrict__ Qf, const float* __restrict__ kv,
    const float* __restrict__ ksum, bf16* __restrict__ O)
{
    int c = blockIdx.x, bh = blockIdx.y;
    int b = bh >> 3, h = bh & 7;
    __shared__ short kvs[64 * 72];        // kvT[d'][e], rows padded to 72 (144B, 16B-aligned)
    int tid = threadIdx.x;
    const float* kvsrc = kv + (size_t)bh * 4096;
    for (int i = tid; i < 4096; i += 256) {
        int e = i >> 6, dp = i & 63;      // kvf[e][d'] -> kvs[d'][e]
        kvs[dp * 72 + e] = f2b_raw(kvsrc[i]);
    }
    int lane = tid & 63, w = tid >> 6;
    int l16 = lane & 15, quad = lane >> 4;

    // den B-fragment: B[k][0] = ksum[k], other cols 0
    b8v kd[2];
    short* kdp = (short*)kd;
#pragma unroll
    for (int kk = 0; kk < 2; ++kk)
#pragma unroll
        for (int j = 0; j < 8; ++j)
            kdp[kk * 8 + j] = (l16 == 0) ? f2b_raw(ksum[bh * 64 + kk * 32 + quad * 8 + j]) : (short)0;
    __syncthreads();

    int rbase = c * 256 + w * 64;
    const short* Qs = (const short*)Qf;
    f4v acc[4][4] = {};
    f4v aden[4] = {};
#pragma unroll
    for (int kk = 0; kk < 2; ++kk) {
        b8v bfr[4];
#pragma unroll
        for (int ni = 0; ni < 4; ++ni)
            bfr[ni] = *(const b8v*)&kvs[(ni * 16 + l16) * 72 + kk * 32 + quad * 8];
#pragma unroll
        for (int mi = 0; mi < 4; ++mi) {
            int grow = rbase + mi * 16 + l16;
            b8v af = {};
            if (grow < cT)
                af = *(const b8v*)(Qs + ((size_t)(b * cT + grow)) * cD + h * cE + kk * 32 + quad * 8);
#pragma unroll
            for (int ni = 0; ni < 4; ++ni)
                acc[mi][ni] = __builtin_amdgcn_mfma_f32_16x16x32_bf16(af, bfr[ni], acc[mi][ni], 0, 0, 0);
            aden[mi] = __builtin_amdgcn_mfma_f32_16x16x32_bf16(af, kd[kk], aden[mi], 0, 0, 0);
        }
    }

#pragma unroll
    for (int mi = 0; mi < 4; ++mi) {
#pragma unroll
        for (int r = 0; r < 4; ++r) {
            float den = __shfl(aden[mi][r], lane & 48);   // broadcast from col-0 lane of this quad
            float z = 1.f / (den + 1e-6f);
            int grow = rbase + mi * 16 + quad * 4 + r;
            if (grow < cT) {
                size_t base = ((size_t)(b * cT + grow)) * cD + h * cE;
#pragma unroll
                for (int ni = 0; ni < 4; ++ni)
                    O[base + ni * 16 + l16] = f2b(acc[mi][ni][r] * z);
            }
        }
    }
}

// out = LN(a + b) * g + be ; 4 rows/block (one wave per row), s8v loads,
// wave-local shfl_xor reduction -> no LDS, no barriers.
template <int DUAL>
__global__ __launch_bounds__(256) void add_ln2(
    const bf16* __restrict__ a, const bf16* __restrict__ b,
    const bf16* __restrict__ g, const bf16* __restrict__ be,
    bf16* __restrict__ out, void* __restrict__ dyn_out,
    const int* __restrict__ fl, size_t dyn_off)
{
    int w = threadIdx.x >> 6, l = threadIdx.x & 63;
    int row = blockIdx.x * 4 + w;
    size_t base = (size_t)row * cD + l * 8;
    s8v va = *(const s8v*)((const short*)a + base);
    s8v vb = *(const s8v*)((const short*)b + base);
    float x[8];
    float s1 = 0.f, s2 = 0.f;
#pragma unroll
    for (int j = 0; j < 8; ++j) {
        x[j] = b2f_raw(va[j]) + b2f_raw(vb[j]);
        s1 += x[j];
        s2 += x[j] * x[j];
    }
#pragma unroll
    for (int off = 32; off; off >>= 1) { s1 += __shfl_xor(s1, off); s2 += __shfl_xor(s2, off); }
    float mean = s1 * (1.f / cD);
    float var = s2 * (1.f / cD) - mean * mean;
    float inv = rsqrtf(var + 1e-5f);
    s8v vg = *(const s8v*)((const short*)g + l * 8);
    s8v vbe = *(const s8v*)((const short*)be + l * 8);
    s8v ov;
    float y[8];
#pragma unroll
    for (int j = 0; j < 8; ++j) {
        y[j] = (x[j] - mean) * inv * b2f_raw(vg[j]) + b2f_raw(vbe[j]);
        ov[j] = f2b_raw(y[j]);
    }
    *(s8v*)((short*)out + base) = ov;
    if (DUAL) {
        int bf = *fl;
        if (bf) {
            *(s8v*)((short*)dyn_out + dyn_off + base) = ov;
        } else {
            float* fo = (float*)dyn_out + dyn_off + base;
            f4v o0, o1;
#pragma unroll
            for (int j = 0; j < 4; ++j) { o0[j] = y[j]; o1[j] = y[4 + j]; }
            *(f4v*)fo = o0;
            *(f4v*)(fo + 4) = o1;
        }
    }
}

// XT[b,o,n,d] = sum_l ttw[o,l]*t_out[b,l,n,d] + ttb[o]   (8 d-elems per thread)
__global__ void tout2_kernel(const bf16* __restrict__ tout, const bf16* __restrict__ ttw,
                             const bf16* __restrict__ ttb, bf16* __restrict__ XT)
{
    size_t idx8 = ((size_t)blockIdx.x * 256 + threadIdx.x) * 8;
    if (idx8 >= SZ) return;
    int d = (int)(idx8 & (cD - 1));
    size_t r = idx8 >> 9;
    int n = (int)(r % cN);
    size_t r2 = r / cN;
    int o = (int)(r2 % cO);
    int b = (int)(r2 / cO);
    float tb = tofl(ttb[o]);
    float acc[8];
#pragma unroll
    for (int j = 0; j < 8; ++j) acc[j] = tb;
    size_t base = ((size_t)b * cT + n) * cD + d;
    const short* ts = (const short*)tout;
#pragma unroll
    for (int l = 0; l < cL; ++l) {
        float wv = tofl(ttw[o * cL + l]);
        s8v v = *(const s8v*)(ts + base + (size_t)l * cN * cD);
#pragma unroll
        for (int j = 0; j < 8; ++j) acc[j] += wv * b2f_raw(v[j]);
    }
    s8v ov;
#pragma unroll
    for (int j = 0; j < 8; ++j) ov[j] = f2b_raw(acc[j]);
    *(s8v*)((short*)XT + idx8) = ov;
}

// At3[s][m][n] = adj[n,m,s]  (row stride 208, bf16)
__global__ void extract_adjT(const void* __restrict__ adj, bf16* __restrict__ At3,
                             const int* __restrict__ fl)
{
    int bf = *fl;
    int idx = blockIdx.x * 256 + threadIdx.x;
    if (idx >= cNG * cN * cN) return;
    int s = idx / (cN * cN);
    int rem = idx - s * cN * cN;
    int m = rem / cN;
    int n = rem - m * cN;
    At3[((size_t)s * cN + m) * 208 + n] = f2b(ldin(adj, (size_t)(n * cN + m) * cNG + s, bf));
}

// dts[b,o,n,d] = (G + gb[o,d]) * bng[o,d] + bnb[o,d]   (8 elems/thread)
__global__ void dts8(const float* __restrict__ g, const bf16* __restrict__ gb,
                     const bf16* __restrict__ bng, const bf16* __restrict__ bnb,
                     void* __restrict__ out, const int* __restrict__ fl)
{
    int bf = *fl;
    size_t idx8 = ((size_t)blockIdx.x * 256 + threadIdx.x) * 8;
    if (idx8 >= SZ) return;
    int d = (int)(idx8 & (cD - 1));
    size_t r = idx8 >> 9;
    int o = (int)((r / cN) % cO);
    int od = o * cD + d;
    f4v g0 = *(const f4v*)(g + idx8);
    f4v g1 = *(const f4v*)(g + idx8 + 4);
    s8v vgb = *(const s8v*)((const short*)gb + od);
    s8v vbg = *(const s8v*)((const short*)bng + od);
    s8v vbb = *(const s8v*)((const short*)bnb + od);
    float y[8];
#pragma unroll
    for (int j = 0; j < 4; ++j) {
        y[j]     = (g0[j] + b2f_raw(vgb[j]))     * b2f_raw(vbg[j])     + b2f_raw(vbb[j]);
        y[4 + j] = (g1[j] + b2f_raw(vgb[4 + j])) * b2f_raw(vbg[4 + j]) + b2f_raw(vbb[4 + j]);
    }
    if (bf) {
        s8v ov;
#pragma unroll
        for (int j = 0; j < 8; ++j) ov[j] = f2b_raw(y[j]);
        *(s8v*)((short*)out + idx8) = ov;
    } else {
        float* fo = (float*)out + idx8;
        f4v o0, o1;
#pragma unroll
        for (int j = 0; j < 4; ++j) { o0[j] = y[j]; o1[j] = y[4 + j]; }
        *(f4v*)fo = o0;
        *(f4v*)(fo + 4) = o1;
    }
}

// ---------------- host helpers ----------------
static inline dim3 g2(int M, int N, int bz) { return dim3((N + 127) / 128, (M + 127) / 128, bz); }
static inline int gcv(size_t n) { return (int)((n + 2047) / 2048); }

static void run_attn(const bf16* Aq, const bf16* Akv, const bf16* wT, const bf16* bias,
                     bf16* Q, bf16* K, bf16* V, bf16* outp,
                     float* kvp, float* ksp, float* kvf, float* ksf, hipStream_t s)
{
    mgemm_f<1, 2, 0><<<g2(cBT, cD, 1), 256, 0, s>>>(Aq,  wT,          Q, bias,          cBT, cD, cD, cD, cD, cD, 0, 0, 0, 1, 1, 0, 0);
    mgemm_f<1, 2, 0><<<g2(cBT, cD, 1), 256, 0, s>>>(Akv, wT + DD,     K, bias + cD,     cBT, cD, cD, cD, cD, cD, 0, 0, 0, 1, 1, 0, 0);
    mgemm_f<1, 0, 0><<<g2(cBT, cD, 1), 256, 0, s>>>(Akv, wT + 2 * DD, V, bias + 2 * cD, cBT, cD, cD, cD, cD, cD, 0, 0, 0, 1, 1, 0, 0);
    kv_part<<<dim3(64, KVCH), 256, 0, s>>>(K, V, kvp, ksp);
    kv_reduce<<<1040, 256, 0, s>>>(kvp, ksp, kvf, ksf);
    attn_o3<<<dim3((cT + 255) / 256, 64), 256, 0, s>>>(Q, kvf, ksf, Q);
    mgemm_f<1, 0, 0><<<g2(cBT, cD, 1), 256, 0, s>>>(Q, wT + 3 * DD, outp, bias + 3 * cD, cBT, cD, cD, cD, cD, cD, 0, 0, 0, 1, 1, 0, 0);
}

static void run_ffn(const bf16* inp, const bf16* w1T, const bf16* b1,
                    const bf16* w2T, const bf16* b2, bf16* mid, bf16* outp, hipStream_t s)
{
    const int MH = cBT / 2;
    for (int h = 0; h < 2; ++h) {
        const bf16* ip = inp + (size_t)h * MH * cD;
        bf16* op = outp + (size_t)h * MH * cD;
        mgemm_f<1, 1, 0><<<g2(MH, cF, 1), 256, 0, s>>>(ip, w1T, mid, b1, MH, cF, cD, cD, cD, cF, 0, 0, 0, 1, 1, 0, 0);
        mgemm_f<1, 0, 0><<<g2(MH, cD, 1), 256, 0, s>>>(mid, w2T, op, b2, MH, cD, cF, cF, cF, cD, 0, 0, 0, 1, 1, 0, 0);
    }
}

// ---------------- entry point ----------------
extern "C" void kernel_launch(void* const* d_in, const int* in_sizes, int n_in,
                              void* d_out, int out_size, void* d_ws, size_t ws_size,
                              hipStream_t stream)
{
    const void* x    = d_in[0];
    const void* st   = d_in[1];
    const void* adj  = d_in[3];
    const void* eqw  = d_in[4];
    const void* eqb  = d_in[5];
    const void* ew1  = d_in[6];
    const void* eb1  = d_in[7];
    const void* ew2  = d_in[8];
    const void* eb2  = d_in[9];
    const void* elng = d_in[10];
    const void* elnb = d_in[11];
    const void* dsw  = d_in[12];
    const void* dsb  = d_in[13];
    const void* dcw  = d_in[14];
    const void* dcb  = d_in[15];
    const void* dw1  = d_in[16];
    const void* db1  = d_in[17];
    const void* dw2  = d_in[18];
    const void* db2  = d_in[19];
    const void* dlng = d_in[20];
    const void* dlnb = d_in[21];
    const void* ttw  = d_in[22];
    const void* ttb  = d_in[23];
    const void* tsw  = d_in[24];
    const void* tsb  = d_in[25];
    const void* gw   = d_in[26];
    const void* gb   = d_in[27];
    const void* bng  = d_in[28];
    const void* bnb  = d_in[29];

    bf16* P = (bf16*)d_ws;
    size_t off = 0;
    auto alloc = [&](size_t n) { size_t o = off; off += (n + 127) & ~(size_t)127; return o; };

    size_t eqwT = alloc(4 * DD);
    size_t dswT = alloc(4 * DD);
    size_t dcwT = alloc(4 * DD);
    size_t ew1T = alloc((size_t)cD * cF);
    size_t ew2T = alloc((size_t)cD * cF);
    size_t dw1T = alloc((size_t)cD * cF);
    size_t dw2T = alloc((size_t)cD * cF);
    size_t gwB  = alloc((size_t)cO * cD * 4608);
    size_t tswB = alloc((size_t)cN * cD);
    size_t xb   = alloc(SZ);
    size_t stb  = alloc(SZ);
    size_t eqbB = alloc(4 * cD), eb1B = alloc(cF), eb2B = alloc(cD);
    size_t elngB = alloc(2 * cD), elnbB = alloc(2 * cD);
    size_t dsbB = alloc(4 * cD), dcbB = alloc(4 * cD);
    size_t db1B = alloc(cF), db2B = alloc(cD);
    size_t dlngB = alloc(3 * cD), dlnbB = alloc(3 * cD);
    size_t ttwB = alloc(cO * cL), ttbB = alloc(cO), tsbB = alloc(cN);
    size_t gbB = alloc(cO * cD), bngB = alloc(cO * cD), bnbB = alloc(cO * cD);
    size_t at3 = alloc((size_t)cNG * cN * 208);
    size_t slots = alloc(6 * SZ);
    bf16* S[6];
    for (int i = 0; i < 6; ++i) S[i] = P + slots + (size_t)i * SZ;

    float* F0  = (float*)(P + off);
    float* kvp = F0;                              // KVCH*64*64*64
    float* ksp = kvp + (size_t)KVCH * 262144;     // KVCH*4096
    float* kvf = ksp + (size_t)KVCH * 4096;       // 64*64*64
    float* ksf = kvf + 262144;                    // 4096
    int* flag  = (int*)(ksf + 4096);

    detect_kernel<<<1, 256, 0, stream>>>(x, flag);

    // ---- converts ----
    for (int i = 0; i < 4; ++i) {
        cvt_trt<<<dim3(8, 8), 256, 0, stream>>>(P + eqwT + i * DD, eqw, flag, cD, cD, (size_t)i * DD);
        cvt_trt<<<dim3(8, 8), 256, 0, stream>>>(P + dswT + i * DD, dsw, flag, cD, cD, (size_t)i * DD);
        cvt_trt<<<dim3(8, 8), 256, 0, stream>>>(P + dcwT + i * DD, dcw, flag, cD, cD, (size_t)i * DD);
    }
    cvt_trt<<<dim3(8, 32), 256, 0, stream>>>(P + ew1T, ew1, flag, cD, cF, 0);
    cvt_trt<<<dim3(32, 8), 256, 0, stream>>>(P + ew2T, ew2, flag, cF, cD, 0);
    cvt_trt<<<dim3(8, 32), 256, 0, stream>>>(P + dw1T, dw1, flag, cD, cF, 0);
    cvt_trt<<<dim3(32, 8), 256, 0, stream>>>(P + dw2T, dw2, flag, cF, cD, 0);
    cvt_copy8<<<gcv((size_t)cO * cD * 4608), 256, 0, stream>>>(P + gwB, gw, flag, (size_t)cO * cD * 4608, 0);
    cvt_copy8<<<gcv((size_t)cN * cD), 256, 0, stream>>>(P + tswB, tsw, flag, (size_t)cN * cD, 0);
    cvt_copy8<<<gcv(SZ), 256, 0, stream>>>(P + xb, x, flag, SZ, 0);
    cvt_copy8<<<gcv(SZ), 256, 0, stream>>>(P + stb, st, flag, SZ, 0);
    cvt_copy8<<<1, 256, 0, stream>>>(P + eqbB, eqb, flag, 4 * cD, 0);
    cvt_copy8<<<1, 256, 0, stream>>>(P + eb1B, eb1, flag, cF, 0);
    cvt_copy8<<<1, 256, 0, stream>>>(P + eb2B, eb2, flag, cD, 0);
    cvt_copy8<<<1, 256, 0, stream>>>(P + elngB, elng, flag, 2 * cD, 0);
    cvt_copy8<<<1, 256, 0, stream>>>(P + elnbB, elnb, flag, 2 * cD, 0);
    cvt_copy8<<<1, 256, 0, stream>>>(P + dsbB, dsb, flag, 4 * cD, 0);
    cvt_copy8<<<1, 256, 0, stream>>>(P + dcbB, dcb, flag, 4 * cD, 0);
    cvt_copy8<<<1, 256, 0, stream>>>(P + db1B, db1, flag, cF, 0);
    cvt_copy8<<<1, 256, 0, stream>>>(P + db2B, db2, flag, cD, 0);
    cvt_copy8<<<1, 256, 0, stream>>>(P + dlngB, dlng, flag, 3 * cD, 0);
    cvt_copy8<<<1, 256, 0, stream>>>(P + dlnbB, dlnb, flag, 3 * cD, 0);
    cvt_copy8<<<1, 256, 0, stream>>>(P + ttwB, ttw, flag, cO * cL, 0);
    cvt_copy8<<<1, 256, 0, stream>>>(P + ttbB, ttb, flag, cO, 0);
    cvt_copy8<<<1, 256, 0, stream>>>(P + tsbB, tsb, flag, cN, 0);
    cvt_copy8<<<3, 256, 0, stream>>>(P + gbB, gb, flag, cO * cD, 0);
    cvt_copy8<<<3, 256, 0, stream>>>(P + bngB, bng, flag, cO * cD, 0);
    cvt_copy8<<<3, 256, 0, stream>>>(P + bnbB, bnb, flag, cO * cD, 0);

    // ===== encoder =====
    run_attn(P + xb, P + xb, P + eqwT, P + eqbB, S[0], S[1], S[2], S[3], kvp, ksp, kvf, ksf, stream);
    add_ln2<0><<<cBT / 4, 256, 0, stream>>>(P + xb, S[3], P + elngB, P + elnbB, S[4], nullptr, flag, 0);   // y
    run_ffn(S[4], P + ew1T, P + eb1B, P + ew2T, P + eb2B, S[0], S[2], stream);
    add_ln2<0><<<cBT / 4, 256, 0, stream>>>(S[4], S[2], P + elngB + cD, P + elnbB + cD, S[5], nullptr, flag, 0);  // t_out

    // ===== decoder self-attn =====
    run_attn(P + stb, P + stb, P + dswT, P + dsbB, S[0], S[1], S[2], S[3], kvp, ksp, kvf, ksf, stream);
    add_ln2<0><<<cBT / 4, 256, 0, stream>>>(P + stb, S[3], P + dlngB, P + dlnbB, S[4], nullptr, flag, 0);  // q1

    // ===== decoder cross-attn (Q from q1, KV from t_out) =====
    run_attn(S[4], S[5], P + dcwT, P + dcbB, S[0], S[1], S[2], S[3], kvp, ksp, kvf, ksf, stream);
    add_ln2<0><<<cBT / 4, 256, 0, stream>>>(S[4], S[3], P + dlngB + cD, P + dlnbB + cD, S[4], nullptr, flag, 0);  // q2 (in-place)

    // ===== decoder FFN + s_out =====
    run_ffn(S[4], P + dw1T, P + db1B, P + dw2T, P + db2B, S[0], S[2], stream);
    add_ln2<1><<<cBT / 4, 256, 0, stream>>>(S[4], S[2], P + dlngB + 2 * cD, P + dlnbB + 2 * cD, S[3], d_out, flag, SZ);

    // ===== temporal projection X_T -> S0 =====
    tout2_kernel<<<(int)(SZ / 2048), 256, 0, stream>>>(S[5], P + ttwB, P + ttbB, S[0]);

    // ===== adaptive adjacency AadT[bz][m][n] (ldc=208) -> S1 =====
    mgemm_f<2, 0, 0><<<g2(cN, cN, cB * cO), 256, 0, stream>>>(
        P + tswB, S[3], S[1], P + tsbB, cN, cN, cD, cD, cD, 208,
        0, (long)cN * cD, (long)cN * 208, 1, 0, 0, 0);

    extract_adjT<<<(cNG * cN * cN + 255) / 256, 256, 0, stream>>>(adj, P + at3, flag);

    // ===== graph diffusion + GCN =====
    float* G = (float*)S[4];           // S4+S5 = SZ floats

    auto accum = [&](const bf16* Feat, int f) {
        mgemm_f<0, 0, 2><<<g2(cN, cD, cB * cO), 256, 0, stream>>>(
            Feat, P + gwB, G, nullptr, cN, cD, cD, cD, 4608, cD,
            (long)cN * cD, (long)cD * 4608, (long)cN * cD, 0, cO, 0, (long)f * cD);
    };
    auto featmul = [&](const bf16* A, long sA, int modA, long aoff0, const bf16* Fin, bf16* Fout) {
        mgemm<false, 0, 0, 0><<<g2(cN, cD, cB * cO), 256, 0, stream>>>(
            A, Fin, Fout, nullptr, cN, cD, cN, 208, cD, cD,
            sA, (long)cN * cD, (long)cN * cD, modA, 0, aoff0, 0);
    };

    // first accumulate WRITES G (OUT=1) -> no zerof pass needed
    mgemm_f<0, 0, 1><<<g2(cN, cD, cB * cO), 256, 0, stream>>>(
        S[0], P + gwB, G, nullptr, cN, cD, cD, cD, 4608, cD,
        (long)cN * cD, (long)cD * 4608, (long)cN * cD, 0, cO, 0, 0);
    for (int s = 0; s < cNG; ++s) {
        featmul(P + at3, 0, 1, (long)s * cN * 208, S[0], S[3]);
        accum(S[3], 2 * s + 1);
        featmul(P + at3, 0, 1, (long)s * cN * 208, S[3], S[2]);
        accum(S[2], 2 * s + 2);
    }
    featmul(S[1], (long)cN * 208, 0, 0, S[0], S[3]);
    accum(S[3], 7);
    featmul(S[1], (long)cN * 208, 0, 0, S[3], S[2]);
    accum(S[2], 8);

    // ===== epilogue =====
    dts8<<<(int)(SZ / 2048), 256, 0, stream>>>(G, P + gbB, P + bngB, P + bnbB, d_out, flag);
}